// Round 11
// baseline (378.514 us; speedup 1.0000x reference)
//
#include <hip/hip_runtime.h>
#include <cstdint>
#include <cstddef>

using u16 = unsigned short;
using u32 = unsigned int;
using u64 = unsigned long long;

typedef __bf16 bf16x8 __attribute__((ext_vector_type(8)));
typedef float f32x4 __attribute__((ext_vector_type(4)));

static constexpr int Bb = 2, S = 2048, D = 1024, H = 16, W = 64, F = 4096;
static constexpr int M = Bb * S;   // 4096 rows

__device__ __forceinline__ float bf2f(u16 u) {
  union { u32 i; float f; } c; c.i = ((u32)u) << 16; return c.f;
}
__device__ __forceinline__ u16 f2bf(float f) {
  union { float f; u32 i; } c; c.f = f;
  u32 i = c.i;
  u32 r = (i + 0x7fffu + ((i >> 16) & 1u)) >> 16;
  return (u16)r;
}
__device__ __forceinline__ u16 f2bf_cvt(float f) {
  __bf16 b = (__bf16)f;
  union { __bf16 b; u16 u; } c; c.b = b; return c.u;
}
__device__ __forceinline__ __bf16 u2b(u16 x) {
  union { u16 u; __bf16 b; } c; c.u = x; return c.b;
}
__device__ __forceinline__ void stv(float* p, size_t i, float v) { p[i] = v; }
__device__ __forceinline__ void stv(u16* p, size_t i, float v)   { p[i] = f2bf(v); }
__device__ __forceinline__ float ldv(const float* p, size_t i) { return p[i]; }
__device__ __forceinline__ float ldv(const u16* p, size_t i)   { return bf2f(p[i]); }

// vectorized 4-element load/store (d % 4 == 0)
__device__ __forceinline__ void ld4(const float* p, size_t d, float* o) {
  float4 v = *(const float4*)(p + d);
  o[0] = v.x; o[1] = v.y; o[2] = v.z; o[3] = v.w;
}
__device__ __forceinline__ void ld4(const u16* p, size_t d, float* o) {
  union { uint2 q; u16 e[4]; } u;
  u.q = *(const uint2*)(p + d);
#pragma unroll
  for (int j = 0; j < 4; j++) o[j] = bf2f(u.e[j]);
}
__device__ __forceinline__ void st4(float* p, size_t d, const float* v) {
  *(float4*)(p + d) = make_float4(v[0], v[1], v[2], v[3]);
}
__device__ __forceinline__ void st4(u16* p, size_t d, const float* v) {
  u16 e[4] = { f2bf(v[0]), f2bf(v[1]), f2bf(v[2]), f2bf(v[3]) };
  *(uint2*)(p + d) = *(const uint2*)e;
}

__device__ __forceinline__ void async_cp16(const u16* g, u16* l) {
  __builtin_amdgcn_global_load_lds(
      (const __attribute__((address_space(1))) void*)g,
      (__attribute__((address_space(3))) void*)l, 16, 0, 0);
}

// 8x8 super-tile block swizzle for L2 locality. Requires gridDim.x%8==0,
// gridDim.y%8==0. 64 consecutive blocks -> 8 A-tiles + 8 B-tiles (~4MB).
__device__ __forceinline__ void swizzle8(int& bx, int& by) {
  int bid = blockIdx.y * gridDim.x + blockIdx.x;
  int gpr = gridDim.x >> 3;
  int grp = bid >> 6, rem = bid & 63;
  int gm = grp / gpr, gn = grp - gm * gpr;
  by = gm * 8 + (rem >> 3);
  bx = gn * 8 + (rem & 7);
}

// ---------------------------------------------------------------------------
// fp32 -> bf16 elementwise convert (n % 1024 == 0)
// ---------------------------------------------------------------------------
__global__ __launch_bounds__(256) void conv_x_kernel(
    const float* __restrict__ src, u16* __restrict__ dst)
{
  int i = (blockIdx.x * 256 + threadIdx.x) * 4;
  float4 v = *(const float4*)(src + i);
  u16 r[4] = { f2bf(v.x), f2bf(v.y), f2bf(v.z), f2bf(v.w) };
  *(uint2*)(dst + i) = *(const uint2*)r;
}

// ---------------------------------------------------------------------------
// Weight transpose+convert: src (K,N) fp32 -> dst (N,K) bf16. 64x64 tiles.
// ---------------------------------------------------------------------------
__global__ __launch_bounds__(256) void transpose_w_kernel(
    const float* __restrict__ src, u16* __restrict__ dst, int K, int N)
{
  __shared__ __align__(16) u16 T[64][72];
  const int tid = threadIdx.x;
  const int n0 = blockIdx.x * 64, k0 = blockIdx.y * 64;
#pragma unroll
  for (int t = 0; t < 4; t++) {
    int idx = tid + t * 256;           // 0..1023 float4s
    int r = idx >> 4, c4 = (idx & 15) * 4;
    float4 v = *(const float4*)(src + (size_t)(k0 + r) * N + n0 + c4);
    T[c4 + 0][r] = f2bf(v.x); T[c4 + 1][r] = f2bf(v.y);
    T[c4 + 2][r] = f2bf(v.z); T[c4 + 3][r] = f2bf(v.w);
  }
  __syncthreads();
#pragma unroll
  for (int t = 0; t < 2; t++) {
    int idx = tid + t * 256;           // 0..511 uint4s
    int r = idx >> 3, c8 = (idx & 7) * 8;
    *(uint4*)(dst + (size_t)(n0 + r) * K + k0 + c8) = *(const uint4*)(&T[r][c8]);
  }
}

// ---------------------------------------------------------------------------
// 4 x (1024,1024) weight transposes in one dispatch (z selects weight).
// dstb contiguous: wqkvT(3M elems) then woT(1M elems).
// ---------------------------------------------------------------------------
__global__ __launch_bounds__(256) void transpose_w4_kernel(
    const float* __restrict__ wq, const float* __restrict__ wk,
    const float* __restrict__ wv, const float* __restrict__ wo,
    u16* __restrict__ dstb)
{
  __shared__ __align__(16) u16 T[64][72];
  const int tid = threadIdx.x;
  const int z = blockIdx.z;
  const float* src = z == 0 ? wq : z == 1 ? wk : z == 2 ? wv : wo;
  u16* dst = dstb + (size_t)z * 1024 * 1024;
  const int n0 = blockIdx.x * 64, k0 = blockIdx.y * 64;
#pragma unroll
  for (int t = 0; t < 4; t++) {
    int idx = tid + t * 256;
    int r = idx >> 4, c4 = (idx & 15) * 4;
    float4 v = *(const float4*)(src + (size_t)(k0 + r) * D + n0 + c4);
    T[c4 + 0][r] = f2bf(v.x); T[c4 + 1][r] = f2bf(v.y);
    T[c4 + 2][r] = f2bf(v.z); T[c4 + 3][r] = f2bf(v.w);
  }
  __syncthreads();
#pragma unroll
  for (int t = 0; t < 2; t++) {
    int idx = tid + t * 256;
    int r = idx >> 3, c8 = (idx & 7) * 8;
    *(uint4*)(dst + (size_t)(n0 + r) * D + k0 + c8) = *(const uint4*)(&T[r][c8]);
  }
}

// ---------------------------------------------------------------------------
// 256x256-tile GEMM template, 2 MERGED phases per K-tile (r11: halve the
// s_barrier count — r10 counters showed ~60% of tile time unexplained by
// LDS+MFMA demand; 8 barriers/tile at 2 waves/SIMD is the residual suspect).
// C = epi(A(M,GK) @ BT(GN,GK)^T + bias), bf16 out. NT = GK/64 K-tiles.
// 512 threads = 8 waves (2m x 4n); per-wave 128x64 out = 8x4 16x16 frags.
// LDS 128 KB: A,B each [2 dbuf][2 half][128 rows][64 k] bf16.
// T2 swizzle (rule #21, both-sides): 16B slot' = slot ^ (row&7) via
// pre-swizzled GLOBAL source (linear global_load_lds dest) + XOR'd ds_read.
// NO sched_barrier pins (m141 + r8: 2x regression).
// Schedule per K-tile t (buf = t&1):
//  phase A: read af[mh0](8 b128) + bf0(4) + bf1(4); stage A(t+1) h0+h1 (4);
//           barrier; prio1; 32 MFMA (Q(0,0)+Q(0,1)); prio0; barrier
//  phase B: read af[mh1](8); stage B(t+2) h0+h1 (4);
//           barrier; prio1; 32 MFMA (Q(1,1)+Q(1,0)); prio0;
//           vmcnt(4); barrier
// Ledger (8 issues/tile): vmcnt(4) leaves exactly B(t+2)'s 4 (newest) ->
// A(t+1), B(t+1) landed before tile t+1 phase A reads. Region safety:
// B(t+2)->BL[buf] staged >=1 barrier after BL[buf]'s last read (phase A);
// A(t+1)->AL[buf^1] >=2 barriers after its last read (tile t-1 phase B).
// Prologue 12 issues + vmcnt(4). Ring-clamp at tail.
// EPI: 1 = exact gelu -> C[row*GN+col]; 2 = qkv permute (sel/c, q scaled).
// SWZ: true = swizzle8; false = T1 XCD-chunk swizzle (nwg%8==0, bijective).
// ---------------------------------------------------------------------------
template<int GN, int GK, int EPI, bool SWZ>
__global__ __launch_bounds__(512, 2) void gemm256(
    const u16* __restrict__ A, const u16* __restrict__ BT,
    const float* __restrict__ bias, u16* __restrict__ C, float scale)
{
  constexpr int NT = GK / 64;
  __shared__ __align__(16) u16 AL[2][2][128 * 64];
  __shared__ __align__(16) u16 BL[2][2][128 * 64];
  const int tid = threadIdx.x;
  const int wave = tid >> 6, lane = tid & 63;
  const int quad = lane >> 4, l16 = lane & 15;
  const int wm = wave >> 2, wn = wave & 3;
  int bx, by;
  if (SWZ) {
    swizzle8(bx, by);
  } else {
    int bid = blockIdx.y * gridDim.x + blockIdx.x;
    int cpx = (gridDim.x * gridDim.y) >> 3;
    int swz = (bid & 7) * cpx + (bid >> 3);
    bx = swz % gridDim.x; by = swz / gridDim.x;
  }
  const int m0 = by * 256, n0 = bx * 256;
  const int lr = lane >> 3;
  const int kc8 = ((lane & 7) ^ lr) * 8;          // u16 units
  const int xb = (l16 & 7) * 16;
  const int brow0 = (wn & 1) * 64;                // B row base within half
  const char* abase = (const char*)&AL[0][wm][0];
  const char* bbase = (const char*)&BL[0][wn >> 1][0];
  constexpr int BUFB = 2 * 128 * 64 * 2;          // byte stride AL[1]-AL[0]

  f32x4 acc[8][4] = {};

  auto stA = [&](int t, int buf, int half) {      // A(t) one half, 2 issues
#pragma unroll
    for (int j = 0; j < 2; j++) {
      const u16* g = A + (size_t)(m0 + half * 128 + (j * 8 + wave) * 8 + lr) * GK
                       + t * 64 + kc8;
      async_cp16(g, &AL[buf][half][(j * 8 + wave) * 512]);
    }
  };
  auto stB = [&](int t, int buf, int half) {      // B(t) one half, 2 issues
#pragma unroll
    for (int j = 0; j < 2; j++) {
      const u16* g = BT + (size_t)(n0 + half * 128 + (j * 8 + wave) * 8 + lr) * GK
                        + t * 64 + kc8;
      async_cp16(g, &BL[buf][half][(j * 8 + wave) * 512]);
    }
  };

  stA(0, 0, 0); stA(0, 0, 1);
  stB(0, 0, 0); stB(0, 0, 1);
  stB(1, 1, 0); stB(1, 1, 1);
  asm volatile("s_waitcnt vmcnt(4)" ::: "memory");
  __builtin_amdgcn_s_barrier();

  bf16x8 af[4][2], bf0[2][2], bf1v[2][2];

#pragma unroll 2
  for (int t = 0; t < NT; t++) {
    const int buf = t & 1;
    const char* ab = abase + buf * BUFB;
    const char* bb = bbase + buf * BUFB;

    // ---- phase A: Q(0,0) + Q(0,1) ----
#pragma unroll
    for (int i = 0; i < 4; i++)
#pragma unroll
      for (int s = 0; s < 2; s++)
        af[i][s] = *(const bf16x8*)(ab + (i * 16 + l16) * 128 + (((s * 4 + quad) * 16) ^ xb));
#pragma unroll
    for (int j = 0; j < 2; j++)
#pragma unroll
      for (int s = 0; s < 2; s++)
        bf0[j][s] = *(const bf16x8*)(bb + (brow0 + j * 16 + l16) * 128 + (((s * 4 + quad) * 16) ^ xb));
#pragma unroll
    for (int j = 0; j < 2; j++)
#pragma unroll
      for (int s = 0; s < 2; s++)
        bf1v[j][s] = *(const bf16x8*)(bb + (brow0 + 32 + j * 16 + l16) * 128 + (((s * 4 + quad) * 16) ^ xb));
    stA((t + 1) & (NT - 1), buf ^ 1, 0);
    stA((t + 1) & (NT - 1), buf ^ 1, 1);
    __builtin_amdgcn_s_barrier();
    __builtin_amdgcn_s_setprio(1);
#pragma unroll
    for (int i = 0; i < 4; i++)
#pragma unroll
      for (int j = 0; j < 2; j++)
#pragma unroll
        for (int s = 0; s < 2; s++)
          acc[i][j] = __builtin_amdgcn_mfma_f32_16x16x32_bf16(af[i][s], bf0[j][s], acc[i][j], 0, 0, 0);
#pragma unroll
    for (int i = 0; i < 4; i++)
#pragma unroll
      for (int j = 0; j < 2; j++)
#pragma unroll
        for (int s = 0; s < 2; s++)
          acc[i][2 + j] = __builtin_amdgcn_mfma_f32_16x16x32_bf16(af[i][s], bf1v[j][s], acc[i][2 + j], 0, 0, 0);
    __builtin_amdgcn_s_setprio(0);
    __builtin_amdgcn_s_barrier();

    // ---- phase B: Q(1,1) + Q(1,0) ----
#pragma unroll
    for (int i = 0; i < 4; i++)
#pragma unroll
      for (int s = 0; s < 2; s++)
        af[i][s] = *(const bf16x8*)(ab + (64 + i * 16 + l16) * 128 + (((s * 4 + quad) * 16) ^ xb));
    stB((t + 2) & (NT - 1), buf, 0);
    stB((t + 2) & (NT - 1), buf, 1);
    __builtin_amdgcn_s_barrier();
    __builtin_amdgcn_s_setprio(1);
#pragma unroll
    for (int i = 0; i < 4; i++)
#pragma unroll
      for (int j = 0; j < 2; j++)
#pragma unroll
        for (int s = 0; s < 2; s++)
          acc[4 + i][2 + j] = __builtin_amdgcn_mfma_f32_16x16x32_bf16(af[i][s], bf1v[j][s], acc[4 + i][2 + j], 0, 0, 0);
#pragma unroll
    for (int i = 0; i < 4; i++)
#pragma unroll
      for (int j = 0; j < 2; j++)
#pragma unroll
        for (int s = 0; s < 2; s++)
          acc[4 + i][j] = __builtin_amdgcn_mfma_f32_16x16x32_bf16(af[i][s], bf0[j][s], acc[4 + i][j], 0, 0, 0);
    __builtin_amdgcn_s_setprio(0);
    asm volatile("s_waitcnt vmcnt(4)" ::: "memory");
    __builtin_amdgcn_s_barrier();
  }

  asm volatile("s_waitcnt vmcnt(0)" ::: "memory");

  // epilogue
#pragma unroll
  for (int i = 0; i < 8; i++) {
#pragma unroll
    for (int j = 0; j < 4; j++) {
#pragma unroll
      for (int r = 0; r < 4; r++) {
        int row = m0 + wm * 128 + i * 16 + quad * 4 + r;
        int col = n0 + wn * 64 + j * 16 + l16;
        float val = acc[i][j][r] + bias[col];
        if (EPI == 1) {
          val = 0.5f * val * (1.0f + erff(val * 0.70710678118654752f));
          C[(size_t)row * GN + col] = f2bf(val);
        } else {  // EPI == 2: fused qkv permute, scale on q
          int sel = col >> 10, c = col & 1023;       // D = 1024
          if (sel == 0) val *= scale;
          int bb2 = row >> 11, ss = row & 2047;      // S = 2048
          int hh = c >> 6,  ww = c & 63;             // W = 64
          u16* dst = C + (size_t)sel * M * D;
          dst[(((size_t)(bb2 * H + hh) * S) + ss) * W + ww] = f2bf(val);
        }
      }
    }
  }
}

// ---------------------------------------------------------------------------
// FFN2 256x128-tile 8-phase split-K GEMM. Grid (D/128, M/256, 2) = 256
// blocks (1/CU). See round-5 comments for the phase/vmcnt ledger.
// (Unchanged this round — control for the gemm256 phase-merge A/B.)
// ---------------------------------------------------------------------------
__global__ __launch_bounds__(512, 2) void gemm_ffn2_splitk(
    const u16* __restrict__ A, const u16* __restrict__ BT,
    float* __restrict__ P0, float* __restrict__ P1)
{
  constexpr int GK = F, NT = 32;
  __shared__ __align__(16) u16 AL[2][2][128 * 64];   // 64 KB
  __shared__ __align__(16) u16 BL[2][128 * 64];      // 32 KB
  const int tid = threadIdx.x;
  const int wave = tid >> 6, lane = tid & 63;
  const int quad = lane >> 4, l16 = lane & 15;
  const int wm = wave >> 1, wn = wave & 1;           // 4m x 2n
  int bx, by; swizzle8(bx, by);
  const int m0 = by * 256, n0 = bx * 128;
  const int kbase = blockIdx.z * (F / 2);
  const int lr = lane >> 3;
  const int kc8 = ((lane & 7) ^ lr) * 8;             // u16 units
  const int xb = (l16 & 7) * 16;
  const int arow0 = (wm & 1) * 64;                   // row base within mhalf
  const int brow0 = wn * 64;
  const char* abase = (const char*)&AL[0][wm >> 1][0];
  const char* bbase = (const char*)&BL[0][0];
  constexpr int ABUF = 2 * 128 * 64 * 2;             // AL[1]-AL[0] bytes
  constexpr int BBUF = 128 * 64 * 2;                 // BL[1]-BL[0] bytes

  f32x4 acc[4][4] = {};

  auto stA2 = [&](int t, int buf, int rp) {          // rounds rp*2..rp*2+1
#pragma unroll
    for (int rr = 0; rr < 2; rr++) {
      int rd = rp * 2 + rr;
      const u16* g = A + (size_t)(m0 + rd * 64 + wave * 8 + lr) * GK
                       + kbase + t * 64 + kc8;
      async_cp16(g, &AL[buf][rd >> 1][((rd & 1) * 8 + wave) * 512]);
    }
  };
  auto stB1 = [&](int t, int buf, int rd) {          // one round
    const u16* g = BT + (size_t)(n0 + rd * 64 + wave * 8 + lr) * GK
                      + kbase + t * 64 + kc8;
    async_cp16(g, &BL[buf][(rd * 8 + wave) * 512]);
  };

  // prologue
  stA2(0, 0, 0); stA2(0, 0, 1);
  stB1(0, 0, 0); stB1(0, 0, 1);
  stB1(1, 1, 0); stB1(1, 1, 1);
  asm volatile("s_waitcnt vmcnt(2)" ::: "memory");
  __builtin_amdgcn_s_barrier();

  bf16x8 af[2][2], bf0[2][2], bf1v[2][2];

#pragma unroll 2
  for (int t = 0; t < NT; t++) {
    const int buf = t & 1;
    const char* ab = abase + buf * ABUF;
    const char* bb = bbase + buf * BBUF;

    // ---- phase 0: i01 x j01 ----
#pragma unroll
    for (int i = 0; i < 2; i++)
#pragma unroll
      for (int s = 0; s < 2; s++)
        af[i][s] = *(const bf16x8*)(ab + (arow0 + i * 16 + l16) * 128 + (((s * 4 + quad) * 16) ^ xb));
#pragma unroll
    for (int j = 0; j < 2; j++)
#pragma unroll
      for (int s = 0; s < 2; s++)
        bf0[j][s] = *(const bf16x8*)(bb + (brow0 + j * 16 + l16) * 128 + (((s * 4 + quad) * 16) ^ xb));
    stA2((t + 1) & (NT - 1), buf ^ 1, 0);
    __builtin_amdgcn_s_barrier();
    __builtin_amdgcn_s_setprio(1);
#pragma unroll
    for (int i = 0; i < 2; i++)
#pragma unroll
      for (int j = 0; j < 2; j++)
#pragma unroll
        for (int s = 0; s < 2; s++)
          acc[i][j] = __builtin_amdgcn_mfma_f32_16x16x32_bf16(af[i][s], bf0[j][s], acc[i][j], 0, 0, 0);
    __builtin_amdgcn_s_setprio(0);
    __builtin_amdgcn_s_barrier();

    // ---- phase 1: i01 x j23 ----
#pragma unroll
    for (int j = 0; j < 2; j++)
#pragma unroll
      for (int s = 0; s < 2; s++)
        bf1v[j][s] = *(const bf16x8*)(bb + (brow0 + 32 + j * 16 + l16) * 128 + (((s * 4 + quad) * 16) ^ xb));
    stA2((t + 1) & (NT - 1), buf ^ 1, 1);
    __builtin_amdgcn_s_barrier();
    __builtin_amdgcn_s_setprio(1);
#pragma unroll
    for (int i = 0; i < 2; i++)
#pragma unroll
      for (int j = 0; j < 2; j++)
#pragma unroll
        for (int s = 0; s < 2; s++)
          acc[i][2 + j] = __builtin_amdgcn_mfma_f32_16x16x32_bf16(af[i][s], bf1v[j][s], acc[i][2 + j], 0, 0, 0);
    __builtin_amdgcn_s_setprio(0);
    __builtin_amdgcn_s_barrier();

    // ---- phase 2: i23 x j23 ----
#pragma unroll
    for (int i = 0; i < 2; i++)
#pragma unroll
      for (int s = 0; s < 2; s++)
        af[i][s] = *(const bf16x8*)(ab + (arow0 + 32 + i * 16 + l16) * 128 + (((s * 4 + quad) * 16) ^ xb));
    stB1((t + 2) & (NT - 1), buf, 0);
    __builtin_amdgcn_s_barrier();
    __builtin_amdgcn_s_setprio(1);
#pragma unroll
    for (int i = 0; i < 2; i++)
#pragma unroll
      for (int j = 0; j < 2; j++)
#pragma unroll
        for (int s = 0; s < 2; s++)
          acc[2 + i][2 + j] = __builtin_amdgcn_mfma_f32_16x16x32_bf16(af[i][s], bf1v[j][s], acc[2 + i][2 + j], 0, 0, 0);
    __builtin_amdgcn_s_setprio(0);
    __builtin_amdgcn_s_barrier();

    // ---- phase 3: i23 x j01 ----
    stB1((t + 2) & (NT - 1), buf, 1);
    __builtin_amdgcn_s_barrier();
    __builtin_amdgcn_s_setprio(1);
#pragma unroll
    for (int i = 0; i < 2; i++)
#pragma unroll
      for (int j = 0; j < 2; j++)
#pragma unroll
        for (int s = 0; s < 2; s++)
          acc[2 + i][j] = __builtin_amdgcn_mfma_f32_16x16x32_bf16(af[i][s], bf0[j][s], acc[2 + i][j], 0, 0, 0);
    __builtin_amdgcn_s_setprio(0);
    asm volatile("s_waitcnt vmcnt(2)" ::: "memory");
    __builtin_amdgcn_s_barrier();
  }

  asm volatile("s_waitcnt vmcnt(0)" ::: "memory");

  float* P = blockIdx.z ? P1 : P0;
#pragma unroll
  for (int i = 0; i < 4; i++) {
#pragma unroll
    for (int j = 0; j < 4; j++) {
#pragma unroll
      for (int r = 0; r < 4; r++) {
        int row = m0 + wm * 64 + i * 16 + quad * 4 + r;
        int col = n0 + wn * 64 + j * 16 + l16;
        P[(size_t)row * D + col] = acc[i][j][r];
      }
    }
  }
}

// ---------------------------------------------------------------------------
// 128x64-tile GEMM (N=1024 matmuls), BK=64, 8x8 L2 swizzle.
// Waves 2x2; each wave 64(m) x 32(n) -> acc[4][2], 16 MFMA per stage.
// ---------------------------------------------------------------------------
template<typename TC>
__global__ __launch_bounds__(256) void gemm_bt_n64(
    const u16* __restrict__ A, const u16* __restrict__ BT,
    const float* __restrict__ bias, TC* __restrict__ C,
    int N, int K)
{
  __shared__ __align__(16) u16 As[2][128 * 32];
  __shared__ __align__(16) u16 Bs[2][64 * 32];
  const int tid = threadIdx.x;
  const int wave = tid >> 6, lane = tid & 63;
  const int quad = lane >> 4, l16 = lane & 15;
  int bx, by; swizzle8(bx, by);
  const int m0 = by * 128, n0 = bx * 64;
  const int wm = (wave >> 1) * 64, wn = (wave & 1) * 32;
  const int srow = lane >> 2;
  const int skoff = (lane & 3) * 8;

  f32x4 acc[4][2] = {};

  for (int k0 = 0; k0 < K; k0 += 64) {
#pragma unroll
    for (int h = 0; h < 2; h++) {
#pragma unroll
      for (int t = 0; t < 2; t++) {
        int slot = wave * 2 + t;
        int row = slot * 16 + srow;
        async_cp16(A + (size_t)(m0 + row) * K + k0 + h * 32 + skoff, As[h] + slot * 512);
      }
      int row = wave * 16 + srow;
      async_cp16(BT + (size_t)(n0 + row) * K + k0 + h * 32 + skoff, Bs[h] + wave * 512);
    }
    __syncthreads();

#pragma unroll
    for (int h = 0; h < 2; h++) {
      bf16x8 af[4], bfv[2];
#pragma unroll
      for (int i = 0; i < 4; i++)
        af[i] = *(const bf16x8*)(As[h] + (wm + i * 16 + l16) * 32 + quad * 8);
#pragma unroll
      for (int j = 0; j < 2; j++)
        bfv[j] = *(const bf16x8*)(Bs[h] + (wn + j * 16 + l16) * 32 + quad * 8);
#pragma unroll
      for (int i = 0; i < 4; i++)
#pragma unroll
        for (int j = 0; j < 2; j++)
          acc[i][j] = __builtin_amdgcn_mfma_f32_16x16x32_bf16(af[i], bfv[j], acc[i][j], 0, 0, 0);
    }
    __syncthreads();
  }

#pragma unroll
  for (int i = 0; i < 4; i++) {
#pragma unroll
    for (int j = 0; j < 2; j++) {
#pragma unroll
      for (int r = 0; r < 4; r++) {
        int row = m0 + wm + i * 16 + quad * 4 + r;
        int col = n0 + wn + j * 16 + l16;
        stv(C, (size_t)row * N + col, acc[i][j][r] + bias[col]);
      }
    }
  }
}

// ---------------------------------------------------------------------------
// V transpose: (BH, S, W) -> (BH, W, S), 64x64 tiles via LDS.
// ---------------------------------------------------------------------------
__global__ __launch_bounds__(256) void transpose_v_kernel(
    const u16* __restrict__ v, u16* __restrict__ vt)
{
  __shared__ __align__(16) u16 T[64][72];
  const int bh = blockIdx.y, k0 = blockIdx.x * 64, tid = threadIdx.x;
#pragma unroll
  for (int it = 0; it < 2; it++) {
    int vv = tid + it * 256;
    int key = vv >> 3, w0 = (vv & 7) * 8;
    union { uint4 q; u16 e[8]; } u;
    u.q = *(const uint4*)(v + ((size_t)bh * S + k0 + key) * W + w0);
#pragma unroll
    for (int j = 0; j < 8; j++) T[w0 + j][key] = u.e[j];
  }
  __syncthreads();
#pragma unroll
  for (int it = 0; it < 2; it++) {
    int vv = tid + it * 256;
    int w = vv >> 3, koff = (vv & 7) * 8;
    *(uint4*)(vt + ((size_t)bh * W + w) * S + k0 + koff) = *(const uint4*)(&T[w][koff]);
  }
}

// ---------------------------------------------------------------------------
// Flash attention (MFMA). QBLK=256: 4 waves x 64 q-rows (4 groups of 16).
// Swapped QK^T, ballot mask (+ all-ones fast path), b64 P-stores, key-split
// 2-way, XOR-swizzled LDS. Grid (S/256, BH, 2) = 512 blocks.
// ---------------------------------------------------------------------------
__global__ __launch_bounds__(256) void fattn_kernel(
    const u16* __restrict__ q, const u16* __restrict__ k,
    const u16* __restrict__ vt, const int* __restrict__ mask,
    u16* __restrict__ o_parts, float* __restrict__ l_parts)
{
  __shared__ __align__(16) u16 QP[2][256][32];  // Q staging, then P tiles
  __shared__ __align__(16) u16 Kl[2][64][32];   // K tile [key][w]
  __shared__ __align__(16) u16 Vl[2][64][32];   // V^T tile [w][key]

  const int tid = threadIdx.x, wave = tid >> 6, lane = tid & 63;
  const int quad = lane >> 4, l16 = lane & 15;
  const int bh = blockIdx.y, b = bh >> 4, h = bh & 15;
  const int q0 = blockIdx.x * 256;
  const int half = blockIdx.z;
  const int kbase = half * (S / 2);             // first key of this half
  const int wq0 = wave * 64;                    // wave's 64 q-rows
  const int sr  = tid >> 3;              // 0..31
  const int sg  = tid & 7;               // chunk along W: 0..7
  const int sp  = sg >> 2;               // plane (cols 0-31 / 32-63)
  const int sc0 = sg * 8;                // global col (u16 units)
  const int ssw = (((sg & 3) ^ ((sr >> 1) & 3)) << 3);
  const int xr = (l16 >> 1) & 3;
  const int rq = ((quad ^ xr) << 3);

  // stage Q tile 256x64 (swizzled)
#pragma unroll
  for (int t = 0; t < 8; t++) {
    int row = sr + t * 32;
    *(uint4*)(&QP[sp][row][ssw]) =
        *(const uint4*)(q + ((size_t)bh * S + q0 + row) * W + sc0);
  }
  __syncthreads();
  bf16x8 aq[4][2];
#pragma unroll
  for (int g = 0; g < 4; g++)
#pragma unroll
    for (int kc = 0; kc < 2; kc++)
      aq[g][kc] = *(const bf16x8*)(&QP[kc][wq0 + g * 16 + l16][rq]);

  bf16x8 ones;
  {
    u16 ov = (l16 == 0) ? (u16)0x3F80 : (u16)0;
#pragma unroll
    for (int j = 0; j < 8; j++) ones[j] = u2b(ov);
  }

  f32x4 o_acc[4][4] = {};
  f32x4 l_acc[4] = {};

  uint4 kr0, kr1, vr0, vr1;
  int mv;
  kr0 = *(const uint4*)(k  + ((size_t)bh * S + kbase + sr     ) * W + sc0);
  kr1 = *(const uint4*)(k  + ((size_t)bh * S + kbase + sr + 32) * W + sc0);
  vr0 = *(const uint4*)(vt + ((size_t)bh * W + sr     ) * S + kbase + sc0);
  vr1 = *(const uint4*)(vt + ((size_t)bh * W + sr + 32) * S + kbase + sc0);
  mv  = mask[b * S + kbase + lane];

  constexpr int NT = S / 128;   // 16 key tiles per half
  for (int kt = 0; kt < NT; kt++) {
    __syncthreads();
    *(uint4*)(&Kl[sp][sr     ][ssw]) = kr0;
    *(uint4*)(&Kl[sp][sr + 32][ssw]) = kr1;
    *(uint4*)(&Vl[sp][sr     ][ssw]) = vr0;
    *(uint4*)(&Vl[sp][sr + 32][ssw]) = vr1;
    u64 km = __ballot(mv != 0);
    __syncthreads();

    if (kt + 1 < NT) {
      int kn = kbase + (kt + 1) * 64;
      kr0 = *(const uint4*)(k  + ((size_t)bh * S + kn + sr     ) * W + sc0);
      kr1 = *(const uint4*)(k  + ((size_t)bh * S + kn + sr + 32) * W + sc0);
      vr0 = *(const uint4*)(vt + ((size_t)bh * W + sr     ) * S + kn + sc0);
      vr1 = *(const uint4*)(vt + ((size_t)bh * W + sr + 32) * S + kn + sc0);
      mv  = mask[b * S + kn + lane];
    }

    const bool allm = (km == ~0ull);   // wave-uniform fast path
#pragma unroll
    for (int tn = 0; tn < 4; tn++) {
      bf16x8 bk0 = *(const bf16x8*)(&Kl[0][tn * 16 + l16][rq]);
      bf16x8 bk1 = *(const bf16x8*)(&Kl[1][tn * 16 + l16][rq]);
      u32 nib = (u32)(km >> (tn * 16 + quad * 4)) & 0xFu;
      int slotp = (((tn & 1) * 2 + (quad >> 1)) ^ xr) * 8 + (quad & 1) * 4;
#pragma unroll
      for (int g = 0; g < 4; g++) {
        f32x4 s4 = {};
        s4 = __builtin_amdgcn_mfma_f32_16x16x32_bf16(bk0, aq[g][0], s4, 0, 0, 0);
        s4 = __builtin_amdgcn_mfma_f32_16x16x32_bf16(bk1, aq[g][1], s4, 0, 0, 0);
        union { u64 u; u16 e[4]; } pw;
        if (allm) {
#pragma unroll
          for (int r = 0; r < 4; r++) pw.e[r] = f2bf_cvt(__expf(s4[r]));
        } else {
#pragma unroll
          for (int r = 0; r < 4; r++) {
            float pm = (float)((nib >> r) & 1u);
            pw.e[r] = f2bf_cvt(__expf(s4[r]) * pm);
          }
        }
        *(u64*)(&QP[tn >> 1][wq0 + g * 16 + l16][slotp]) = pw.u;
      }
    }
    // no barrier: P slab is wave-private; same-wave DS ops are ordered

#pragma unroll
    for (int kc = 0; kc < 2; kc++) {
      bf16x8 ap[4];
#pragma unroll
      for (int g = 0; g < 4; g++)
        ap[g] = *(const bf16x8*)(&QP[kc][wq0 + g * 16 + l16][rq]);
#pragma unroll
      for (int tn = 0; tn < 4; tn++) {
        bf16x8 bv = *(const bf16x8*)(&Vl[kc][tn * 16 + l16][rq]);
#pragma unroll
        for (int g = 0; g < 4; g++)
          o_acc[g][tn] = __builtin_amdgcn_mfma_f32_16x16x32_bf16(ap[g], bv, o_acc[g][tn], 0, 0, 0);
      }
#pragma unroll
      for (int g = 0; g < 4; g++)
        l_acc[g] = __builtin_amdgcn_mfma_f32_16x16x32_bf16(ap[g], ones, l_acc[g], 0, 0, 0);
    }
  }

  u16* ob = o_parts + (size_t)half * M * D;
  float* lb = l_parts + (size_t)half * M * H;
#pragma unroll
  for (int g = 0; g < 4; g++) {
#pragma unroll
    for (int r = 0; r < 4; r++) {
      float lsum = __shfl(l_acc[g][r], lane & 0x30);
      int sg2 = q0 + wq0 + g * 16 + quad * 4 + r;
      if (l16 == 0) lb[((size_t)b * S + sg2) * H + h] = lsum;
#pragma unroll
      for (int tn = 0; tn < 4; tn++) {
        ob[((size_t)b * S + sg2) * D + h * W + tn * 16 + l16] = f2bf_cvt(o_acc[g][tn][r]);
      }
    }
  }
}

// ---------------------------------------------------------------------------
// Combine key-split partials: attn = (o0 + o1) / (l0 + l1). In-place on
// half 0 (same-address elementwise -> race-free).
// ---------------------------------------------------------------------------
__global__ __launch_bounds__(256) void combine_attn(
    const u16* __restrict__ o_parts, const float* __restrict__ l_parts,
    u16* __restrict__ attn)
{
  size_t idx = ((size_t)blockIdx.x * 256 + threadIdx.x) * 8;
  int row = (int)(idx >> 10);          // (b*S+s)
  int h = ((int)idx >> 6) & 15;        // head (8 elems stay in one head)
  float l = l_parts[(size_t)row * H + h] + l_parts[(size_t)M * H + (size_t)row * H + h];
  float inv = 1.0f / l;
  union { uint4 v; u16 e[8]; } a, bq, o;
  a.v  = *(const uint4*)(o_parts + idx);
  bq.v = *(const uint4*)(o_parts + (size_t)M * D + idx);
#pragma unroll
  for (int j = 0; j < 8; j++)
    o.e[j] = f2bf((bf2f(a.e[j]) + bf2f(bq.e[j])) * inv);
  *(uint4*)(attn + idx) = o.v;
}

// ---------------------------------------------------------------------------
// Fused residual + LayerNorm, one WAVE per row, vectorized 16B/lane loads
// (G13). grid = M/4 blocks of 256 threads.
// ---------------------------------------------------------------------------
template<typename TA, typename TR, typename TO>
__global__ __launch_bounds__(256) void ln_res_kernel(
    const TA* __restrict__ a, const TR* __restrict__ r,
    const float* __restrict__ g, const float* __restrict__ be,
    TO* __restrict__ out)
{
  const int tid = threadIdx.x, lane = tid & 63;
  const int row = blockIdx.x * 4 + (tid >> 6);
  const TA* ap = a + (size_t)row * D;
  const TR* rp = r + (size_t)row * D;
  float hv[16];
  float s = 0.f;
#pragma unroll
  for (int c4 = 0; c4 < 4; c4++) {
    int d = c4 * 256 + lane * 4;
    float a4[4], r4[4];
    ld4(ap, d, a4); ld4(rp, d, r4);
#pragma unroll
    for (int j = 0; j < 4; j++) { hv[c4 * 4 + j] = a4[j] + r4[j]; s += hv[c4 * 4 + j]; }
  }
#pragma unroll
  for (int d = 1; d < 64; d <<= 1) s += __shfl_xor(s, d);
  float mean = s * (1.0f / D);
  float v = 0.f;
#pragma unroll
  for (int c = 0; c < 16; c++) { float t = hv[c] - mean; v += t * t; }
#pragma unroll
  for (int d = 1; d < 64; d <<= 1) v += __shfl_xor(v, d);
  float inv = rsqrtf(v * (1.0f / D) + 1e-12f);
#pragma unroll
  for (int c4 = 0; c4 < 4; c4++) {
    int d = c4 * 256 + lane * 4;
    float g4[4], b4[4], o4[4];
    ld4(g, d, g4); ld4(be, d, b4);
#pragma unroll
    for (int j = 0; j < 4; j++) o4[j] = g4[j] * ((hv[c4 * 4 + j] - mean) * inv) + b4[j];
    st4(out + (size_t)row * D, d, o4);
  }
}

// ---------------------------------------------------------------------------
// LN2 with split-K FFN2 partials: out = LN(a + p0 + p1 + bias). Vectorized.
// In-place safe when out == p0 (per-thread same-address read/write).
// ---------------------------------------------------------------------------
__global__ __launch_bounds__(256) void ln_res3_kernel(
    const u16* __restrict__ a, const float* __restrict__ p0,
    const float* __restrict__ p1, const float* __restrict__ bias,
    const float* __restrict__ g, const float* __restrict__ be,
    float* __restrict__ out)
{
  const int tid = threadIdx.x, lane = tid & 63;
  const int row = blockIdx.x * 4 + (tid >> 6);
  const u16* ap = a + (size_t)row * D;
  const float* q0 = p0 + (size_t)row * D;
  const float* q1 = p1 + (size_t)row * D;
  float hv[16];
  float s = 0.f;
#pragma unroll
  for (int c4 = 0; c4 < 4; c4++) {
    int d = c4 * 256 + lane * 4;
    float a4[4], x4[4], y4[4], b4[4];
    ld4(ap, d, a4); ld4(q0, d, x4); ld4(q1, d, y4); ld4(bias, d, b4);
#pragma unroll
    for (int j = 0; j < 4; j++) {
      hv[c4 * 4 + j] = a4[j] + x4[j] + y4[j] + b4[j];
      s += hv[c4 * 4 + j];
    }
  }
#pragma unroll
  for (int d = 1; d < 64; d <<= 1) s += __shfl_xor(s, d);
  float mean = s * (1.0f / D);
  float v = 0.f;
#pragma unroll
  for (int c = 0; c < 16; c++) { float t = hv[c] - mean; v += t * t; }
#pragma unroll
  for (int d = 1; d < 64; d <<= 1) v += __shfl_xor(v, d);
  float inv = rsqrtf(v * (1.0f / D) + 1e-12f);
#pragma unroll
  for (int c4 = 0; c4 < 4; c4++) {
    int d = c4 * 256 + lane * 4;
    float g4[4], b4[4], o4[4];
    ld4(g, d, g4); ld4(be, d, b4);
#pragma unroll
    for (int j = 0; j < 4; j++) o4[j] = g4[j] * ((hv[c4 * 4 + j] - mean) * inv) + b4[j];
    st4(out + (size_t)row * D, d, o4);
  }
}

// ---------------------------------------------------------------------------
extern "C" void kernel_launch(void* const* d_in, const int* in_sizes, int n_in,
                              void* d_out, int out_size, void* d_ws, size_t ws_size,
                              hipStream_t stream)
{
  const float* x  = (const float*)d_in[0];
  const int* mask = (const int*)d_in[1];
  const float* wq = (const float*)d_in[2];  const float* bq  = (const float*)d_in[3];
  const float* wk = (const float*)d_in[4];  const float* bk  = (const float*)d_in[5];
  const float* wv = (const float*)d_in[6];  const float* bv  = (const float*)d_in[7];
  const float* wo = (const float*)d_in[8];  const float* bo  = (const float*)d_in[9];
  const float* g1 = (const float*)d_in[10]; const float* b1  = (const float*)d_in[11];
  const float* w1 = (const float*)d_in[12]; const float* bf1 = (const float*)d_in[13];
  const float* w2 = (const float*)d_in[14]; const float* bf2 = (const float*)d_in[15];
  const float* g2 = (const float*)d_in[16]; const float* b2  = (const float*)d_in[17];

  // ws layout (base 48 MB; split-K FFN2 uses [48,64M) when available):
  //  A [0,8M):   wqkvT(6M)+woT(2M); wqkvT dead after QKV -> l_parts(512KB)
  //              lives at [0,0.5M) during fattn; then w1T(8M) -> w2T(8M)
  //  B [8,16M):  xb -> vt -> ff1[0:8M)
  //  C [16,24M): q  -> proj -> ff1[8:16M)
  //  D [24,32M): k  -> ff1[16:24M)
  //  E [32,48M): v(8M, dead after transpose_v) -> o_parts(16M); combine
  //              writes attn in-place over half 0 ([32,40M)) -> ff1[24:32M)
  //  F [40,48M): bqkv(12KB, dead by fattn) -> o_parts half1 -> h1
  //  G [48,64M): FFN2 split-K partial1 (fp32, 16M) -- only if ws_size allows
  //  ff2 partial0 -> d_out; LN2 in place on d_out.
  char* ws = (char*)d_ws;
  const size_t MB = 1024 * 1024;
  u16* wqkvT = (u16*)(ws + 0 * MB);          // (3072, 1024) bf16 (+woT after)
  u16* w1T   = (u16*)(ws + 0 * MB);          // (4096, 1024) after proj
  u16* w2T   = (u16*)(ws + 0 * MB);          // (1024, 4096) after ffn1
  u16* woT   = (u16*)(ws + 6 * MB);          // (1024, 1024)
  u16* xb    = (u16*)(ws + 8 * MB);
  u16* vt    = (u16*)(ws + 8 * MB);
  u16* q     = (u16*)(ws + 16 * MB);
  u16* proj  = (u16*)(ws + 16 * MB);
  u16* kb    = (u16*)(ws + 24 * MB);
  u16* vb    = (u16*)(ws + 32 * MB);
  u16* oparts = (u16*)(ws + 32 * MB);        // 16 MB: 2 x (M,D) bf16 partials
  float* lparts = (float*)(ws + 0 * MB);     // 512 KB: 2 x (M,H) f32
  u16* attn  = (u16*)(ws + 32 * MB);         // combine output (aliases half0)
  u16* ff1   = (u16*)(ws + 8 * MB);          // 32 MB: [8,40)
  float* bqkv = (float*)(ws + 40 * MB);      // 12 KB
  u16* h1    = (u16*)(ws + 40 * MB);
  float* part1 = (float*)(ws + 48 * MB);     // 16 MB (gated on ws_size)
  float* out = (float*)d_out;

  const bool bigws = ws_size >= (size_t)64 * MB;

  dim3 blk(256);

  // prep: x -> bf16; 4 weight transposes in ONE dispatch; bias concat
  conv_x_kernel<<<dim3(M * D / 1024), blk, 0, stream>>>(x, xb);
  transpose_w4_kernel<<<dim3(16, 16, 4), blk, 0, stream>>>(wq, wk, wv, wo, wqkvT);
  hipMemcpyAsync(bqkv,        bq, D * sizeof(float), hipMemcpyDeviceToDevice, stream);
  hipMemcpyAsync(bqkv + 1024, bk, D * sizeof(float), hipMemcpyDeviceToDevice, stream);
  hipMemcpyAsync(bqkv + 2048, bv, D * sizeof(float), hipMemcpyDeviceToDevice, stream);

  // fused QKV GEMM: (M,1024)@(1024,3072), EPI=2 permute. Grid (12,16)=192;
  // SWZ=false -> T1 XCD-chunk swizzle.
  gemm256<3072, 1024, 2, false><<<dim3(3072 / 256, M / 256), dim3(512), 0, stream>>>(
      xb, wqkvT, bqkv, q, 0.125f);

  transpose_v_kernel<<<dim3(S / 64, Bb * H), blk, 0, stream>>>(vb, vt);
  // key-split flash attention: QBLK=256, 512 blocks, partials
  fattn_kernel<<<dim3(S / 256, Bb * H, 2), blk, 0, stream>>>(
      q, kb, vt, mask, oparts, lparts);
  combine_attn<<<dim3(M * D / 2048), blk, 0, stream>>>(oparts, lparts, attn);

  // proj: N=1024 -> 128x64 tiles (512 blocks, 2/CU)
  gemm_bt_n64<u16><<<dim3(D / 64, M / 128), blk, 0, stream>>>(
      attn, woT, bo, proj, D, D);
  ln_res_kernel<float, u16, u16><<<dim3(M / 4), blk, 0, stream>>>(x, proj, g1, b1, h1);

  transpose_w_kernel<<<dim3(F / 64, D / 64), blk, 0, stream>>>(w1, w1T, D, F);
  // FFN1: 256^2 merged-2-phase GEMM (r11 barrier-halving A/B), 256 blocks
  gemm256<4096, 1024, 1, true><<<dim3(F / 256, M / 256), dim3(512), 0, stream>>>(
      h1, w1T, bf1, ff1, 1.0f);

  transpose_w_kernel<<<dim3(D / 64, F / 64), blk, 0, stream>>>(w2, w2T, F, D);
  if (bigws) {
    // FFN2: 256x128-tile 8-phase split-K (unchanged control), fp32 partials;
    // LN2 fuses the combine: out = LN(h1 + p0 + p1 + bf2)
    gemm_ffn2_splitk<<<dim3(D / 128, M / 256, 2), dim3(512), 0, stream>>>(
        ff1, w2T, out, part1);
    ln_res3_kernel<<<dim3(M / 4), blk, 0, stream>>>(h1, out, part1, bf2, g2, b2, out);
  } else {
    // fallback (small workspace): 2-phase 128x64 FFN2 + 2-input LN2
    gemm_bt_n64<float><<<dim3(D / 64, M / 128), blk, 0, stream>>>(
        ff1, w2T, bf2, out, D, F);
    ln_res_kernel<u16, float, float><<<dim3(M / 4), blk, 0, stream>>>(h1, out, g2, b2, out);
  }
}

// Round 12
// 376.451 us; speedup vs baseline: 1.0055x; 1.0055x over previous
//
#include <hip/hip_runtime.h>
#include <cstdint>
#include <cstddef>

using u16 = unsigned short;
using u32 = unsigned int;
using u64 = unsigned long long;

typedef __bf16 bf16x8 __attribute__((ext_vector_type(8)));
typedef float f32x4 __attribute__((ext_vector_type(4)));

static constexpr int Bb = 2, S = 2048, D = 1024, H = 16, W = 64, F = 4096;
static constexpr int M = Bb * S;   // 4096 rows

__device__ __forceinline__ float bf2f(u16 u) {
  union { u32 i; float f; } c; c.i = ((u32)u) << 16; return c.f;
}
__device__ __forceinline__ u16 f2bf(float f) {
  union { float f; u32 i; } c; c.f = f;
  u32 i = c.i;
  u32 r = (i + 0x7fffu + ((i >> 16) & 1u)) >> 16;
  return (u16)r;
}
__device__ __forceinline__ u16 f2bf_cvt(float f) {
  __bf16 b = (__bf16)f;
  union { __bf16 b; u16 u; } c; c.b = b; return c.u;
}
__device__ __forceinline__ __bf16 u2b(u16 x) {
  union { u16 u; __bf16 b; } c; c.u = x; return c.b;
}
__device__ __forceinline__ void stv(float* p, size_t i, float v) { p[i] = v; }
__device__ __forceinline__ void stv(u16* p, size_t i, float v)   { p[i] = f2bf(v); }
__device__ __forceinline__ float ldv(const float* p, size_t i) { return p[i]; }
__device__ __forceinline__ float ldv(const u16* p, size_t i)   { return bf2f(p[i]); }

// vectorized 4-element load/store (d % 4 == 0)
__device__ __forceinline__ void ld4(const float* p, size_t d, float* o) {
  float4 v = *(const float4*)(p + d);
  o[0] = v.x; o[1] = v.y; o[2] = v.z; o[3] = v.w;
}
__device__ __forceinline__ void ld4(const u16* p, size_t d, float* o) {
  union { uint2 q; u16 e[4]; } u;
  u.q = *(const uint2*)(p + d);
#pragma unroll
  for (int j = 0; j < 4; j++) o[j] = bf2f(u.e[j]);
}
__device__ __forceinline__ void st4(float* p, size_t d, const float* v) {
  *(float4*)(p + d) = make_float4(v[0], v[1], v[2], v[3]);
}
__device__ __forceinline__ void st4(u16* p, size_t d, const float* v) {
  u16 e[4] = { f2bf(v[0]), f2bf(v[1]), f2bf(v[2]), f2bf(v[3]) };
  *(uint2*)(p + d) = *(const uint2*)e;
}

__device__ __forceinline__ void async_cp16(const u16* g, u16* l) {
  __builtin_amdgcn_global_load_lds(
      (const __attribute__((address_space(1))) void*)g,
      (__attribute__((address_space(3))) void*)l, 16, 0, 0);
}

// 8x8 super-tile block swizzle for L2 locality. Requires gridDim.x%8==0,
// gridDim.y%8==0. 64 consecutive blocks -> 8 A-tiles + 8 B-tiles (~4MB).
__device__ __forceinline__ void swizzle8(int& bx, int& by) {
  int bid = blockIdx.y * gridDim.x + blockIdx.x;
  int gpr = gridDim.x >> 3;
  int grp = bid >> 6, rem = bid & 63;
  int gm = grp / gpr, gn = grp - gm * gpr;
  by = gm * 8 + (rem >> 3);
  bx = gn * 8 + (rem & 7);
}

// ---------------------------------------------------------------------------
// fp32 -> bf16 elementwise convert (n % 1024 == 0)
// ---------------------------------------------------------------------------
__global__ __launch_bounds__(256) void conv_x_kernel(
    const float* __restrict__ src, u16* __restrict__ dst)
{
  int i = (blockIdx.x * 256 + threadIdx.x) * 4;
  float4 v = *(const float4*)(src + i);
  u16 r[4] = { f2bf(v.x), f2bf(v.y), f2bf(v.z), f2bf(v.w) };
  *(uint2*)(dst + i) = *(const uint2*)r;
}

// ---------------------------------------------------------------------------
// Weight transpose+convert: src (K,N) fp32 -> dst (N,K) bf16. 64x64 tiles.
// ---------------------------------------------------------------------------
__global__ __launch_bounds__(256) void transpose_w_kernel(
    const float* __restrict__ src, u16* __restrict__ dst, int K, int N)
{
  __shared__ __align__(16) u16 T[64][72];
  const int tid = threadIdx.x;
  const int n0 = blockIdx.x * 64, k0 = blockIdx.y * 64;
#pragma unroll
  for (int t = 0; t < 4; t++) {
    int idx = tid + t * 256;           // 0..1023 float4s
    int r = idx >> 4, c4 = (idx & 15) * 4;
    float4 v = *(const float4*)(src + (size_t)(k0 + r) * N + n0 + c4);
    T[c4 + 0][r] = f2bf(v.x); T[c4 + 1][r] = f2bf(v.y);
    T[c4 + 2][r] = f2bf(v.z); T[c4 + 3][r] = f2bf(v.w);
  }
  __syncthreads();
#pragma unroll
  for (int t = 0; t < 2; t++) {
    int idx = tid + t * 256;           // 0..511 uint4s
    int r = idx >> 3, c8 = (idx & 7) * 8;
    *(uint4*)(dst + (size_t)(n0 + r) * K + k0 + c8) = *(const uint4*)(&T[r][c8]);
  }
}

// ---------------------------------------------------------------------------
// 4 x (1024,1024) weight transposes in one dispatch (z selects weight).
// dstb contiguous: wqkvT(3M elems) then woT(1M elems).
// ---------------------------------------------------------------------------
__global__ __launch_bounds__(256) void transpose_w4_kernel(
    const float* __restrict__ wq, const float* __restrict__ wk,
    const float* __restrict__ wv, const float* __restrict__ wo,
    u16* __restrict__ dstb)
{
  __shared__ __align__(16) u16 T[64][72];
  const int tid = threadIdx.x;
  const int z = blockIdx.z;
  const float* src = z == 0 ? wq : z == 1 ? wk : z == 2 ? wv : wo;
  u16* dst = dstb + (size_t)z * 1024 * 1024;
  const int n0 = blockIdx.x * 64, k0 = blockIdx.y * 64;
#pragma unroll
  for (int t = 0; t < 4; t++) {
    int idx = tid + t * 256;
    int r = idx >> 4, c4 = (idx & 15) * 4;
    float4 v = *(const float4*)(src + (size_t)(k0 + r) * D + n0 + c4);
    T[c4 + 0][r] = f2bf(v.x); T[c4 + 1][r] = f2bf(v.y);
    T[c4 + 2][r] = f2bf(v.z); T[c4 + 3][r] = f2bf(v.w);
  }
  __syncthreads();
#pragma unroll
  for (int t = 0; t < 2; t++) {
    int idx = tid + t * 256;
    int r = idx >> 3, c8 = (idx & 7) * 8;
    *(uint4*)(dst + (size_t)(n0 + r) * D + k0 + c8) = *(const uint4*)(&T[r][c8]);
  }
}

// ---------------------------------------------------------------------------
// 256x256-tile GEMM template, 2 merged phases per K-tile (r11; measured
// equal to 4-phase, kept for simplicity). FFN1 only now.
// C = epi(A(M,GK) @ BT(GN,GK)^T + bias), bf16 out. NT = GK/64 K-tiles.
// 512 threads = 8 waves (2m x 4n); per-wave 128x64 out = 8x4 16x16 frags.
// LDS 128 KB. T2 both-sides swizzle (pre-swizzled global src + XOR'd read).
// NO sched_barrier pins (m141 + r8: 2x regression).
// Ledger (8 issues/tile): phase A stages A(t+1) (4), phase B stages B(t+2)
// (4); boundary vmcnt(4) leaves exactly B(t+2) -> A(t+1),B(t+1) landed.
// ---------------------------------------------------------------------------
template<int GN, int GK, int EPI, bool SWZ>
__global__ __launch_bounds__(512, 2) void gemm256(
    const u16* __restrict__ A, const u16* __restrict__ BT,
    const float* __restrict__ bias, u16* __restrict__ C, float scale)
{
  constexpr int NT = GK / 64;
  __shared__ __align__(16) u16 AL[2][2][128 * 64];
  __shared__ __align__(16) u16 BL[2][2][128 * 64];
  const int tid = threadIdx.x;
  const int wave = tid >> 6, lane = tid & 63;
  const int quad = lane >> 4, l16 = lane & 15;
  const int wm = wave >> 2, wn = wave & 3;
  int bx, by;
  if (SWZ) {
    swizzle8(bx, by);
  } else {
    int bid = blockIdx.y * gridDim.x + blockIdx.x;
    int cpx = (gridDim.x * gridDim.y) >> 3;
    int swz = (bid & 7) * cpx + (bid >> 3);
    bx = swz % gridDim.x; by = swz / gridDim.x;
  }
  const int m0 = by * 256, n0 = bx * 256;
  const int lr = lane >> 3;
  const int kc8 = ((lane & 7) ^ lr) * 8;          // u16 units
  const int xb = (l16 & 7) * 16;
  const int brow0 = (wn & 1) * 64;                // B row base within half
  const char* abase = (const char*)&AL[0][wm][0];
  const char* bbase = (const char*)&BL[0][wn >> 1][0];
  constexpr int BUFB = 2 * 128 * 64 * 2;          // byte stride AL[1]-AL[0]

  f32x4 acc[8][4] = {};

  auto stA = [&](int t, int buf, int half) {      // A(t) one half, 2 issues
#pragma unroll
    for (int j = 0; j < 2; j++) {
      const u16* g = A + (size_t)(m0 + half * 128 + (j * 8 + wave) * 8 + lr) * GK
                       + t * 64 + kc8;
      async_cp16(g, &AL[buf][half][(j * 8 + wave) * 512]);
    }
  };
  auto stB = [&](int t, int buf, int half) {      // B(t) one half, 2 issues
#pragma unroll
    for (int j = 0; j < 2; j++) {
      const u16* g = BT + (size_t)(n0 + half * 128 + (j * 8 + wave) * 8 + lr) * GK
                        + t * 64 + kc8;
      async_cp16(g, &BL[buf][half][(j * 8 + wave) * 512]);
    }
  };

  stA(0, 0, 0); stA(0, 0, 1);
  stB(0, 0, 0); stB(0, 0, 1);
  stB(1, 1, 0); stB(1, 1, 1);
  asm volatile("s_waitcnt vmcnt(4)" ::: "memory");
  __builtin_amdgcn_s_barrier();

  bf16x8 af[4][2], bf0[2][2], bf1v[2][2];

#pragma unroll 2
  for (int t = 0; t < NT; t++) {
    const int buf = t & 1;
    const char* ab = abase + buf * BUFB;
    const char* bb = bbase + buf * BUFB;

    // ---- phase A: Q(0,0) + Q(0,1) ----
#pragma unroll
    for (int i = 0; i < 4; i++)
#pragma unroll
      for (int s = 0; s < 2; s++)
        af[i][s] = *(const bf16x8*)(ab + (i * 16 + l16) * 128 + (((s * 4 + quad) * 16) ^ xb));
#pragma unroll
    for (int j = 0; j < 2; j++)
#pragma unroll
      for (int s = 0; s < 2; s++)
        bf0[j][s] = *(const bf16x8*)(bb + (brow0 + j * 16 + l16) * 128 + (((s * 4 + quad) * 16) ^ xb));
#pragma unroll
    for (int j = 0; j < 2; j++)
#pragma unroll
      for (int s = 0; s < 2; s++)
        bf1v[j][s] = *(const bf16x8*)(bb + (brow0 + 32 + j * 16 + l16) * 128 + (((s * 4 + quad) * 16) ^ xb));
    stA((t + 1) & (NT - 1), buf ^ 1, 0);
    stA((t + 1) & (NT - 1), buf ^ 1, 1);
    __builtin_amdgcn_s_barrier();
    __builtin_amdgcn_s_setprio(1);
#pragma unroll
    for (int i = 0; i < 4; i++)
#pragma unroll
      for (int j = 0; j < 2; j++)
#pragma unroll
        for (int s = 0; s < 2; s++)
          acc[i][j] = __builtin_amdgcn_mfma_f32_16x16x32_bf16(af[i][s], bf0[j][s], acc[i][j], 0, 0, 0);
#pragma unroll
    for (int i = 0; i < 4; i++)
#pragma unroll
      for (int j = 0; j < 2; j++)
#pragma unroll
        for (int s = 0; s < 2; s++)
          acc[i][2 + j] = __builtin_amdgcn_mfma_f32_16x16x32_bf16(af[i][s], bf1v[j][s], acc[i][2 + j], 0, 0, 0);
    __builtin_amdgcn_s_setprio(0);
    __builtin_amdgcn_s_barrier();

    // ---- phase B: Q(1,1) + Q(1,0) ----
#pragma unroll
    for (int i = 0; i < 4; i++)
#pragma unroll
      for (int s = 0; s < 2; s++)
        af[i][s] = *(const bf16x8*)(ab + (64 + i * 16 + l16) * 128 + (((s * 4 + quad) * 16) ^ xb));
    stB((t + 2) & (NT - 1), buf, 0);
    stB((t + 2) & (NT - 1), buf, 1);
    __builtin_amdgcn_s_barrier();
    __builtin_amdgcn_s_setprio(1);
#pragma unroll
    for (int i = 0; i < 4; i++)
#pragma unroll
      for (int j = 0; j < 2; j++)
#pragma unroll
        for (int s = 0; s < 2; s++)
          acc[4 + i][2 + j] = __builtin_amdgcn_mfma_f32_16x16x32_bf16(af[i][s], bf1v[j][s], acc[4 + i][2 + j], 0, 0, 0);
#pragma unroll
    for (int i = 0; i < 4; i++)
#pragma unroll
      for (int j = 0; j < 2; j++)
#pragma unroll
        for (int s = 0; s < 2; s++)
          acc[4 + i][j] = __builtin_amdgcn_mfma_f32_16x16x32_bf16(af[i][s], bf0[j][s], acc[4 + i][j], 0, 0, 0);
    __builtin_amdgcn_s_setprio(0);
    asm volatile("s_waitcnt vmcnt(4)" ::: "memory");
    __builtin_amdgcn_s_barrier();
  }

  asm volatile("s_waitcnt vmcnt(0)" ::: "memory");

  // epilogue
#pragma unroll
  for (int i = 0; i < 8; i++) {
#pragma unroll
    for (int j = 0; j < 4; j++) {
#pragma unroll
      for (int r = 0; r < 4; r++) {
        int row = m0 + wm * 128 + i * 16 + quad * 4 + r;
        int col = n0 + wn * 64 + j * 16 + l16;
        float val = acc[i][j][r] + bias[col];
        if (EPI == 1) {
          val = 0.5f * val * (1.0f + erff(val * 0.70710678118654752f));
          C[(size_t)row * GN + col] = f2bf(val);
        } else {  // EPI == 2: fused qkv permute, scale on q
          int sel = col >> 10, c = col & 1023;       // D = 1024
          if (sel == 0) val *= scale;
          int bb2 = row >> 11, ss = row & 2047;      // S = 2048
          int hh = c >> 6,  ww = c & 63;             // W = 64
          u16* dst = C + (size_t)sel * M * D;
          dst[(((size_t)(bb2 * H + hh) * S) + ss) * W + ww] = f2bf(val);
        }
      }
    }
  }
}

// ---------------------------------------------------------------------------
// QKV GEMM, 256x192 tile (r12): grid (3072/192, 4096/256) = (16,16) = 256
// blocks = 1/CU FULL FILL (was 192 blocks = 75% fill at BN=256; QKV measured
// 445 TF = exactly 0.75x FFN1's 593 -> fill defect, not schedule).
// 8 waves (2m x 4n); per-wave 128x48 out = acc[8][3]. LDS 112 KB:
// AL[2 dbuf][2 mhalf][128*64] (64K) + BL[2 dbuf][192*64] (48K).
// Same T2 both-sides swizzle; merged-2-phase schedule.
// Ledger (7 issues/tile): phase A stages A(t+1) rds 0-3 (4); phase B stages
// B(t+2) rds 0-2 (3); boundary vmcnt(3) keeps exactly B(t+2)'s 3 (newest)
// -> A(t+1), B(t+1) landed before tile t+1 phase A reads. Region safety:
// B(t+2)->BL[buf] issued >=1 barrier after BL[buf]'s last read (phase A);
// A(t+1)->AL[buf^1] >=2 barriers after its last read (tile t-1 phase B).
// Prologue: A(0)(4) + B(0)(3) + B(1)(3) = 10 issues; vmcnt(3) -> tile 0
// landed. Ring-clamp at tail. Epilogue = qkv permute (scale on q).
// ---------------------------------------------------------------------------
__global__ __launch_bounds__(512, 2) void gemm256_qkv(
    const u16* __restrict__ A, const u16* __restrict__ BT,
    const float* __restrict__ bias, u16* __restrict__ C, float scale)
{
  constexpr int GK = 1024, NT = GK / 64;
  __shared__ __align__(16) u16 AL[2][2][128 * 64];   // 64 KB
  __shared__ __align__(16) u16 BL[2][192 * 64];      // 48 KB
  const int tid = threadIdx.x;
  const int wave = tid >> 6, lane = tid & 63;
  const int quad = lane >> 4, l16 = lane & 15;
  const int wm = wave >> 2, wn = wave & 3;
  int bx, by; swizzle8(bx, by);                      // (16,16): both %8==0
  const int m0 = by * 256, n0 = bx * 192;
  const int lr = lane >> 3;
  const int kc8 = ((lane & 7) ^ lr) * 8;             // u16 units
  const int xb = (l16 & 7) * 16;
  const int bn0 = wn * 48;                           // wave's B row base
  const char* abase = (const char*)&AL[0][wm][0];
  const char* bbase = (const char*)&BL[0][0];
  constexpr int ABUF = 2 * 128 * 64 * 2;             // AL[1]-AL[0] bytes
  constexpr int BBUF = 192 * 64 * 2;                 // BL[1]-BL[0] bytes

  f32x4 acc[8][3] = {};

  auto stA2 = [&](int t, int buf, int rp) {          // A rounds rp*2..rp*2+1
#pragma unroll
    for (int rr = 0; rr < 2; rr++) {
      int rd = rp * 2 + rr;
      const u16* g = A + (size_t)(m0 + rd * 64 + wave * 8 + lr) * GK
                       + t * 64 + kc8;
      async_cp16(g, &AL[buf][rd >> 1][((rd & 1) * 8 + wave) * 512]);
    }
  };
  auto stB1 = [&](int t, int buf, int rd) {          // B one round (64 rows)
    const u16* g = BT + (size_t)(n0 + rd * 64 + wave * 8 + lr) * GK
                      + t * 64 + kc8;
    async_cp16(g, &BL[buf][(rd * 8 + wave) * 512]);
  };

  // prologue: A(0)(4), B(0)(3), B(1)(3) = 10 issues
  stA2(0, 0, 0); stA2(0, 0, 1);
  stB1(0, 0, 0); stB1(0, 0, 1); stB1(0, 0, 2);
  stB1(1, 1, 0); stB1(1, 1, 1); stB1(1, 1, 2);
  asm volatile("s_waitcnt vmcnt(3)" ::: "memory");
  __builtin_amdgcn_s_barrier();

  bf16x8 af[4][2], bf[3][2];

#pragma unroll 2
  for (int t = 0; t < NT; t++) {
    const int buf = t & 1;
    const char* ab = abase + buf * ABUF;
    const char* bb = bbase + buf * BBUF;

    // ---- phase A: mh0 x all-B ----
#pragma unroll
    for (int i = 0; i < 4; i++)
#pragma unroll
      for (int s = 0; s < 2; s++)
        af[i][s] = *(const bf16x8*)(ab + (i * 16 + l16) * 128 + (((s * 4 + quad) * 16) ^ xb));
#pragma unroll
    for (int j = 0; j < 3; j++)
#pragma unroll
      for (int s = 0; s < 2; s++)
        bf[j][s] = *(const bf16x8*)(bb + (bn0 + j * 16 + l16) * 128 + (((s * 4 + quad) * 16) ^ xb));
    stA2((t + 1) & (NT - 1), buf ^ 1, 0);
    stA2((t + 1) & (NT - 1), buf ^ 1, 1);
    __builtin_amdgcn_s_barrier();
    __builtin_amdgcn_s_setprio(1);
#pragma unroll
    for (int i = 0; i < 4; i++)
#pragma unroll
      for (int j = 0; j < 3; j++)
#pragma unroll
        for (int s = 0; s < 2; s++)
          acc[i][j] = __builtin_amdgcn_mfma_f32_16x16x32_bf16(af[i][s], bf[j][s], acc[i][j], 0, 0, 0);
    __builtin_amdgcn_s_setprio(0);
    __builtin_amdgcn_s_barrier();

    // ---- phase B: mh1 x all-B ----
#pragma unroll
    for (int i = 0; i < 4; i++)
#pragma unroll
      for (int s = 0; s < 2; s++)
        af[i][s] = *(const bf16x8*)(ab + (64 + i * 16 + l16) * 128 + (((s * 4 + quad) * 16) ^ xb));
    stB1((t + 2) & (NT - 1), buf, 0);
    stB1((t + 2) & (NT - 1), buf, 1);
    stB1((t + 2) & (NT - 1), buf, 2);
    __builtin_amdgcn_s_barrier();
    __builtin_amdgcn_s_setprio(1);
#pragma unroll
    for (int i = 0; i < 4; i++)
#pragma unroll
      for (int j = 0; j < 3; j++)
#pragma unroll
        for (int s = 0; s < 2; s++)
          acc[4 + i][j] = __builtin_amdgcn_mfma_f32_16x16x32_bf16(af[i][s], bf[j][s], acc[4 + i][j], 0, 0, 0);
    __builtin_amdgcn_s_setprio(0);
    asm volatile("s_waitcnt vmcnt(3)" ::: "memory");
    __builtin_amdgcn_s_barrier();
  }

  asm volatile("s_waitcnt vmcnt(0)" ::: "memory");

  // epilogue: fused qkv permute (scale on q)
#pragma unroll
  for (int i = 0; i < 8; i++) {
#pragma unroll
    for (int j = 0; j < 3; j++) {
#pragma unroll
      for (int r = 0; r < 4; r++) {
        int row = m0 + wm * 128 + i * 16 + quad * 4 + r;
        int col = n0 + wn * 48 + j * 16 + l16;
        float val = acc[i][j][r] + bias[col];
        int sel = col >> 10, c = col & 1023;       // D = 1024
        if (sel == 0) val *= scale;
        int bb2 = row >> 11, ss = row & 2047;      // S = 2048
        int hh = c >> 6,  ww = c & 63;             // W = 64
        u16* dst = C + (size_t)sel * M * D;
        dst[(((size_t)(bb2 * H + hh) * S) + ss) * W + ww] = f2bf(val);
      }
    }
  }
}

// ---------------------------------------------------------------------------
// FFN2 256x128-tile 8-phase split-K GEMM. Grid (D/128, M/256, 2) = 256
// blocks (1/CU). See round-5 comments for the phase/vmcnt ledger.
// ---------------------------------------------------------------------------
__global__ __launch_bounds__(512, 2) void gemm_ffn2_splitk(
    const u16* __restrict__ A, const u16* __restrict__ BT,
    float* __restrict__ P0, float* __restrict__ P1)
{
  constexpr int GK = F, NT = 32;
  __shared__ __align__(16) u16 AL[2][2][128 * 64];   // 64 KB
  __shared__ __align__(16) u16 BL[2][128 * 64];      // 32 KB
  const int tid = threadIdx.x;
  const int wave = tid >> 6, lane = tid & 63;
  const int quad = lane >> 4, l16 = lane & 15;
  const int wm = wave >> 1, wn = wave & 1;           // 4m x 2n
  int bx, by; swizzle8(bx, by);
  const int m0 = by * 256, n0 = bx * 128;
  const int kbase = blockIdx.z * (F / 2);
  const int lr = lane >> 3;
  const int kc8 = ((lane & 7) ^ lr) * 8;             // u16 units
  const int xb = (l16 & 7) * 16;
  const int arow0 = (wm & 1) * 64;                   // row base within mhalf
  const int brow0 = wn * 64;
  const char* abase = (const char*)&AL[0][wm >> 1][0];
  const char* bbase = (const char*)&BL[0][0];
  constexpr int ABUF = 2 * 128 * 64 * 2;             // AL[1]-AL[0] bytes
  constexpr int BBUF = 128 * 64 * 2;                 // BL[1]-BL[0] bytes

  f32x4 acc[4][4] = {};

  auto stA2 = [&](int t, int buf, int rp) {          // rounds rp*2..rp*2+1
#pragma unroll
    for (int rr = 0; rr < 2; rr++) {
      int rd = rp * 2 + rr;
      const u16* g = A + (size_t)(m0 + rd * 64 + wave * 8 + lr) * GK
                       + kbase + t * 64 + kc8;
      async_cp16(g, &AL[buf][rd >> 1][((rd & 1) * 8 + wave) * 512]);
    }
  };
  auto stB1 = [&](int t, int buf, int rd) {          // one round
    const u16* g = BT + (size_t)(n0 + rd * 64 + wave * 8 + lr) * GK
                      + kbase + t * 64 + kc8;
    async_cp16(g, &BL[buf][(rd * 8 + wave) * 512]);
  };

  // prologue
  stA2(0, 0, 0); stA2(0, 0, 1);
  stB1(0, 0, 0); stB1(0, 0, 1);
  stB1(1, 1, 0); stB1(1, 1, 1);
  asm volatile("s_waitcnt vmcnt(2)" ::: "memory");
  __builtin_amdgcn_s_barrier();

  bf16x8 af[2][2], bf0[2][2], bf1v[2][2];

#pragma unroll 2
  for (int t = 0; t < NT; t++) {
    const int buf = t & 1;
    const char* ab = abase + buf * ABUF;
    const char* bb = bbase + buf * BBUF;

    // ---- phase 0: i01 x j01 ----
#pragma unroll
    for (int i = 0; i < 2; i++)
#pragma unroll
      for (int s = 0; s < 2; s++)
        af[i][s] = *(const bf16x8*)(ab + (arow0 + i * 16 + l16) * 128 + (((s * 4 + quad) * 16) ^ xb));
#pragma unroll
    for (int j = 0; j < 2; j++)
#pragma unroll
      for (int s = 0; s < 2; s++)
        bf0[j][s] = *(const bf16x8*)(bb + (brow0 + j * 16 + l16) * 128 + (((s * 4 + quad) * 16) ^ xb));
    stA2((t + 1) & (NT - 1), buf ^ 1, 0);
    __builtin_amdgcn_s_barrier();
    __builtin_amdgcn_s_setprio(1);
#pragma unroll
    for (int i = 0; i < 2; i++)
#pragma unroll
      for (int j = 0; j < 2; j++)
#pragma unroll
        for (int s = 0; s < 2; s++)
          acc[i][j] = __builtin_amdgcn_mfma_f32_16x16x32_bf16(af[i][s], bf0[j][s], acc[i][j], 0, 0, 0);
    __builtin_amdgcn_s_setprio(0);
    __builtin_amdgcn_s_barrier();

    // ---- phase 1: i01 x j23 ----
#pragma unroll
    for (int j = 0; j < 2; j++)
#pragma unroll
      for (int s = 0; s < 2; s++)
        bf1v[j][s] = *(const bf16x8*)(bb + (brow0 + 32 + j * 16 + l16) * 128 + (((s * 4 + quad) * 16) ^ xb));
    stA2((t + 1) & (NT - 1), buf ^ 1, 1);
    __builtin_amdgcn_s_barrier();
    __builtin_amdgcn_s_setprio(1);
#pragma unroll
    for (int i = 0; i < 2; i++)
#pragma unroll
      for (int j = 0; j < 2; j++)
#pragma unroll
        for (int s = 0; s < 2; s++)
          acc[i][2 + j] = __builtin_amdgcn_mfma_f32_16x16x32_bf16(af[i][s], bf1v[j][s], acc[i][2 + j], 0, 0, 0);
    __builtin_amdgcn_s_setprio(0);
    __builtin_amdgcn_s_barrier();

    // ---- phase 2: i23 x j23 ----
#pragma unroll
    for (int i = 0; i < 2; i++)
#pragma unroll
      for (int s = 0; s < 2; s++)
        af[i][s] = *(const bf16x8*)(ab + (arow0 + 32 + i * 16 + l16) * 128 + (((s * 4 + quad) * 16) ^ xb));
    stB1((t + 2) & (NT - 1), buf, 0);
    __builtin_amdgcn_s_barrier();
    __builtin_amdgcn_s_setprio(1);
#pragma unroll
    for (int i = 0; i < 2; i++)
#pragma unroll
      for (int j = 0; j < 2; j++)
#pragma unroll
        for (int s = 0; s < 2; s++)
          acc[2 + i][2 + j] = __builtin_amdgcn_mfma_f32_16x16x32_bf16(af[i][s], bf1v[j][s], acc[2 + i][2 + j], 0, 0, 0);
    __builtin_amdgcn_s_setprio(0);
    __builtin_amdgcn_s_barrier();

    // ---- phase 3: i23 x j01 ----
    stB1((t + 2) & (NT - 1), buf, 1);
    __builtin_amdgcn_s_barrier();
    __builtin_amdgcn_s_setprio(1);
#pragma unroll
    for (int i = 0; i < 2; i++)
#pragma unroll
      for (int j = 0; j < 2; j++)
#pragma unroll
        for (int s = 0; s < 2; s++)
          acc[2 + i][j] = __builtin_amdgcn_mfma_f32_16x16x32_bf16(af[i][s], bf0[j][s], acc[2 + i][j], 0, 0, 0);
    __builtin_amdgcn_s_setprio(0);
    asm volatile("s_waitcnt vmcnt(2)" ::: "memory");
    __builtin_amdgcn_s_barrier();
  }

  asm volatile("s_waitcnt vmcnt(0)" ::: "memory");

  float* P = blockIdx.z ? P1 : P0;
#pragma unroll
  for (int i = 0; i < 4; i++) {
#pragma unroll
    for (int j = 0; j < 4; j++) {
#pragma unroll
      for (int r = 0; r < 4; r++) {
        int row = m0 + wm * 64 + i * 16 + quad * 4 + r;
        int col = n0 + wn * 64 + j * 16 + l16;
        P[(size_t)row * D + col] = acc[i][j][r];
      }
    }
  }
}

// ---------------------------------------------------------------------------
// 128x64-tile GEMM (N=1024 matmuls), BK=64, 8x8 L2 swizzle.
// Waves 2x2; each wave 64(m) x 32(n) -> acc[4][2], 16 MFMA per stage.
// ---------------------------------------------------------------------------
template<typename TC>
__global__ __launch_bounds__(256) void gemm_bt_n64(
    const u16* __restrict__ A, const u16* __restrict__ BT,
    const float* __restrict__ bias, TC* __restrict__ C,
    int N, int K)
{
  __shared__ __align__(16) u16 As[2][128 * 32];
  __shared__ __align__(16) u16 Bs[2][64 * 32];
  const int tid = threadIdx.x;
  const int wave = tid >> 6, lane = tid & 63;
  const int quad = lane >> 4, l16 = lane & 15;
  int bx, by; swizzle8(bx, by);
  const int m0 = by * 128, n0 = bx * 64;
  const int wm = (wave >> 1) * 64, wn = (wave & 1) * 32;
  const int srow = lane >> 2;
  const int skoff = (lane & 3) * 8;

  f32x4 acc[4][2] = {};

  for (int k0 = 0; k0 < K; k0 += 64) {
#pragma unroll
    for (int h = 0; h < 2; h++) {
#pragma unroll
      for (int t = 0; t < 2; t++) {
        int slot = wave * 2 + t;
        int row = slot * 16 + srow;
        async_cp16(A + (size_t)(m0 + row) * K + k0 + h * 32 + skoff, As[h] + slot * 512);
      }
      int row = wave * 16 + srow;
      async_cp16(BT + (size_t)(n0 + row) * K + k0 + h * 32 + skoff, Bs[h] + wave * 512);
    }
    __syncthreads();

#pragma unroll
    for (int h = 0; h < 2; h++) {
      bf16x8 af[4], bfv[2];
#pragma unroll
      for (int i = 0; i < 4; i++)
        af[i] = *(const bf16x8*)(As[h] + (wm + i * 16 + l16) * 32 + quad * 8);
#pragma unroll
      for (int j = 0; j < 2; j++)
        bfv[j] = *(const bf16x8*)(Bs[h] + (wn + j * 16 + l16) * 32 + quad * 8);
#pragma unroll
      for (int i = 0; i < 4; i++)
#pragma unroll
        for (int j = 0; j < 2; j++)
          acc[i][j] = __builtin_amdgcn_mfma_f32_16x16x32_bf16(af[i], bfv[j], acc[i][j], 0, 0, 0);
    }
    __syncthreads();
  }

#pragma unroll
  for (int i = 0; i < 4; i++) {
#pragma unroll
    for (int j = 0; j < 2; j++) {
#pragma unroll
      for (int r = 0; r < 4; r++) {
        int row = m0 + wm + i * 16 + quad * 4 + r;
        int col = n0 + wn + j * 16 + l16;
        stv(C, (size_t)row * N + col, acc[i][j][r] + bias[col]);
      }
    }
  }
}

// ---------------------------------------------------------------------------
// V transpose: (BH, S, W) -> (BH, W, S), 64x64 tiles via LDS.
// ---------------------------------------------------------------------------
__global__ __launch_bounds__(256) void transpose_v_kernel(
    const u16* __restrict__ v, u16* __restrict__ vt)
{
  __shared__ __align__(16) u16 T[64][72];
  const int bh = blockIdx.y, k0 = blockIdx.x * 64, tid = threadIdx.x;
#pragma unroll
  for (int it = 0; it < 2; it++) {
    int vv = tid + it * 256;
    int key = vv >> 3, w0 = (vv & 7) * 8;
    union { uint4 q; u16 e[8]; } u;
    u.q = *(const uint4*)(v + ((size_t)bh * S + k0 + key) * W + w0);
#pragma unroll
    for (int j = 0; j < 8; j++) T[w0 + j][key] = u.e[j];
  }
  __syncthreads();
#pragma unroll
  for (int it = 0; it < 2; it++) {
    int vv = tid + it * 256;
    int w = vv >> 3, koff = (vv & 7) * 8;
    *(uint4*)(vt + ((size_t)bh * W + w) * S + k0 + koff) = *(const uint4*)(&T[w][koff]);
  }
}

// ---------------------------------------------------------------------------
// Flash attention (MFMA). QBLK=256: 4 waves x 64 q-rows (4 groups of 16).
// Swapped QK^T, ballot mask (+ all-ones fast path), b64 P-stores, key-split
// 2-way, XOR-swizzled LDS. Grid (S/256, BH, 2) = 512 blocks.
// ---------------------------------------------------------------------------
__global__ __launch_bounds__(256) void fattn_kernel(
    const u16* __restrict__ q, const u16* __restrict__ k,
    const u16* __restrict__ vt, const int* __restrict__ mask,
    u16* __restrict__ o_parts, float* __restrict__ l_parts)
{
  __shared__ __align__(16) u16 QP[2][256][32];  // Q staging, then P tiles
  __shared__ __align__(16) u16 Kl[2][64][32];   // K tile [key][w]
  __shared__ __align__(16) u16 Vl[2][64][32];   // V^T tile [w][key]

  const int tid = threadIdx.x, wave = tid >> 6, lane = tid & 63;
  const int quad = lane >> 4, l16 = lane & 15;
  const int bh = blockIdx.y, b = bh >> 4, h = bh & 15;
  const int q0 = blockIdx.x * 256;
  const int half = blockIdx.z;
  const int kbase = half * (S / 2);             // first key of this half
  const int wq0 = wave * 64;                    // wave's 64 q-rows
  const int sr  = tid >> 3;              // 0..31
  const int sg  = tid & 7;               // chunk along W: 0..7
  const int sp  = sg >> 2;               // plane (cols 0-31 / 32-63)
  const int sc0 = sg * 8;                // global col (u16 units)
  const int ssw = (((sg & 3) ^ ((sr >> 1) & 3)) << 3);
  const int xr = (l16 >> 1) & 3;
  const int rq = ((quad ^ xr) << 3);

  // stage Q tile 256x64 (swizzled)
#pragma unroll
  for (int t = 0; t < 8; t++) {
    int row = sr + t * 32;
    *(uint4*)(&QP[sp][row][ssw]) =
        *(const uint4*)(q + ((size_t)bh * S + q0 + row) * W + sc0);
  }
  __syncthreads();
  bf16x8 aq[4][2];
#pragma unroll
  for (int g = 0; g < 4; g++)
#pragma unroll
    for (int kc = 0; kc < 2; kc++)
      aq[g][kc] = *(const bf16x8*)(&QP[kc][wq0 + g * 16 + l16][rq]);

  bf16x8 ones;
  {
    u16 ov = (l16 == 0) ? (u16)0x3F80 : (u16)0;
#pragma unroll
    for (int j = 0; j < 8; j++) ones[j] = u2b(ov);
  }

  f32x4 o_acc[4][4] = {};
  f32x4 l_acc[4] = {};

  uint4 kr0, kr1, vr0, vr1;
  int mv;
  kr0 = *(const uint4*)(k  + ((size_t)bh * S + kbase + sr     ) * W + sc0);
  kr1 = *(const uint4*)(k  + ((size_t)bh * S + kbase + sr + 32) * W + sc0);
  vr0 = *(const uint4*)(vt + ((size_t)bh * W + sr     ) * S + kbase + sc0);
  vr1 = *(const uint4*)(vt + ((size_t)bh * W + sr + 32) * S + kbase + sc0);
  mv  = mask[b * S + kbase + lane];

  constexpr int NT = S / 128;   // 16 key tiles per half
  for (int kt = 0; kt < NT; kt++) {
    __syncthreads();
    *(uint4*)(&Kl[sp][sr     ][ssw]) = kr0;
    *(uint4*)(&Kl[sp][sr + 32][ssw]) = kr1;
    *(uint4*)(&Vl[sp][sr     ][ssw]) = vr0;
    *(uint4*)(&Vl[sp][sr + 32][ssw]) = vr1;
    u64 km = __ballot(mv != 0);
    __syncthreads();

    if (kt + 1 < NT) {
      int kn = kbase + (kt + 1) * 64;
      kr0 = *(const uint4*)(k  + ((size_t)bh * S + kn + sr     ) * W + sc0);
      kr1 = *(const uint4*)(k  + ((size_t)bh * S + kn + sr + 32) * W + sc0);
      vr0 = *(const uint4*)(vt + ((size_t)bh * W + sr     ) * S + kn + sc0);
      vr1 = *(const uint4*)(vt + ((size_t)bh * W + sr + 32) * S + kn + sc0);
      mv  = mask[b * S + kn + lane];
    }

    const bool allm = (km == ~0ull);   // wave-uniform fast path
#pragma unroll
    for (int tn = 0; tn < 4; tn++) {
      bf16x8 bk0 = *(const bf16x8*)(&Kl[0][tn * 16 + l16][rq]);
      bf16x8 bk1 = *(const bf16x8*)(&Kl[1][tn * 16 + l16][rq]);
      u32 nib = (u32)(km >> (tn * 16 + quad * 4)) & 0xFu;
      int slotp = (((tn & 1) * 2 + (quad >> 1)) ^ xr) * 8 + (quad & 1) * 4;
#pragma unroll
      for (int g = 0; g < 4; g++) {
        f32x4 s4 = {};
        s4 = __builtin_amdgcn_mfma_f32_16x16x32_bf16(bk0, aq[g][0], s4, 0, 0, 0);
        s4 = __builtin_amdgcn_mfma_f32_16x16x32_bf16(bk1, aq[g][1], s4, 0, 0, 0);
        union { u64 u; u16 e[4]; } pw;
        if (allm) {
#pragma unroll
          for (int r = 0; r < 4; r++) pw.e[r] = f2bf_cvt(__expf(s4[r]));
        } else {
#pragma unroll
          for (int r = 0; r < 4; r++) {
            float pm = (float)((nib >> r) & 1u);
            pw.e[r] = f2bf_cvt(__expf(s4[r]) * pm);
          }
        }
        *(u64*)(&QP[tn >> 1][wq0 + g * 16 + l16][slotp]) = pw.u;
      }
    }
    // no barrier: P slab is wave-private; same-wave DS ops are ordered

#pragma unroll
    for (int kc = 0; kc < 2; kc++) {
      bf16x8 ap[4];
#pragma unroll
      for (int g = 0; g < 4; g++)
        ap[g] = *(const bf16x8*)(&QP[kc][wq0 + g * 16 + l16][rq]);
#pragma unroll
      for (int tn = 0; tn < 4; tn++) {
        bf16x8 bv = *(const bf16x8*)(&Vl[kc][tn * 16 + l16][rq]);
#pragma unroll
        for (int g = 0; g < 4; g++)
          o_acc[g][tn] = __builtin_amdgcn_mfma_f32_16x16x32_bf16(ap[g], bv, o_acc[g][tn], 0, 0, 0);
      }
#pragma unroll
      for (int g = 0; g < 4; g++)
        l_acc[g] = __builtin_amdgcn_mfma_f32_16x16x32_bf16(ap[g], ones, l_acc[g], 0, 0, 0);
    }
  }

  u16* ob = o_parts + (size_t)half * M * D;
  float* lb = l_parts + (size_t)half * M * H;
#pragma unroll
  for (int g = 0; g < 4; g++) {
#pragma unroll
    for (int r = 0; r < 4; r++) {
      float lsum = __shfl(l_acc[g][r], lane & 0x30);
      int sg2 = q0 + wq0 + g * 16 + quad * 4 + r;
      if (l16 == 0) lb[((size_t)b * S + sg2) * H + h] = lsum;
#pragma unroll
      for (int tn = 0; tn < 4; tn++) {
        ob[((size_t)b * S + sg2) * D + h * W + tn * 16 + l16] = f2bf_cvt(o_acc[g][tn][r]);
      }
    }
  }
}

// ---------------------------------------------------------------------------
// Combine key-split partials: attn = (o0 + o1) / (l0 + l1). In-place on
// half 0 (same-address elementwise -> race-free).
// ---------------------------------------------------------------------------
__global__ __launch_bounds__(256) void combine_attn(
    const u16* __restrict__ o_parts, const float* __restrict__ l_parts,
    u16* __restrict__ attn)
{
  size_t idx = ((size_t)blockIdx.x * 256 + threadIdx.x) * 8;
  int row = (int)(idx >> 10);          // (b*S+s)
  int h = ((int)idx >> 6) & 15;        // head (8 elems stay in one head)
  float l = l_parts[(size_t)row * H + h] + l_parts[(size_t)M * H + (size_t)row * H + h];
  float inv = 1.0f / l;
  union { uint4 v; u16 e[8]; } a, bq, o;
  a.v  = *(const uint4*)(o_parts + idx);
  bq.v = *(const uint4*)(o_parts + (size_t)M * D + idx);
#pragma unroll
  for (int j = 0; j < 8; j++)
    o.e[j] = f2bf((bf2f(a.e[j]) + bf2f(bq.e[j])) * inv);
  *(uint4*)(attn + idx) = o.v;
}

// ---------------------------------------------------------------------------
// Fused residual + LayerNorm, one WAVE per row, vectorized 16B/lane loads
// (G13). grid = M/4 blocks of 256 threads.
// ---------------------------------------------------------------------------
template<typename TA, typename TR, typename TO>
__global__ __launch_bounds__(256) void ln_res_kernel(
    const TA* __restrict__ a, const TR* __restrict__ r,
    const float* __restrict__ g, const float* __restrict__ be,
    TO* __restrict__ out)
{
  const int tid = threadIdx.x, lane = tid & 63;
  const int row = blockIdx.x * 4 + (tid >> 6);
  const TA* ap = a + (size_t)row * D;
  const TR* rp = r + (size_t)row * D;
  float hv[16];
  float s = 0.f;
#pragma unroll
  for (int c4 = 0; c4 < 4; c4++) {
    int d = c4 * 256 + lane * 4;
    float a4[4], r4[4];
    ld4(ap, d, a4); ld4(rp, d, r4);
#pragma unroll
    for (int j = 0; j < 4; j++) { hv[c4 * 4 + j] = a4[j] + r4[j]; s += hv[c4 * 4 + j]; }
  }
#pragma unroll
  for (int d = 1; d < 64; d <<= 1) s += __shfl_xor(s, d);
  float mean = s * (1.0f / D);
  float v = 0.f;
#pragma unroll
  for (int c = 0; c < 16; c++) { float t = hv[c] - mean; v += t * t; }
#pragma unroll
  for (int d = 1; d < 64; d <<= 1) v += __shfl_xor(v, d);
  float inv = rsqrtf(v * (1.0f / D) + 1e-12f);
#pragma unroll
  for (int c4 = 0; c4 < 4; c4++) {
    int d = c4 * 256 + lane * 4;
    float g4[4], b4[4], o4[4];
    ld4(g, d, g4); ld4(be, d, b4);
#pragma unroll
    for (int j = 0; j < 4; j++) o4[j] = g4[j] * ((hv[c4 * 4 + j] - mean) * inv) + b4[j];
    st4(out + (size_t)row * D, d, o4);
  }
}

// ---------------------------------------------------------------------------
// LN2 with split-K FFN2 partials: out = LN(a + p0 + p1 + bias). Vectorized.
// In-place safe when out == p0 (per-thread same-address read/write).
// ---------------------------------------------------------------------------
__global__ __launch_bounds__(256) void ln_res3_kernel(
    const u16* __restrict__ a, const float* __restrict__ p0,
    const float* __restrict__ p1, const float* __restrict__ bias,
    const float* __restrict__ g, const float* __restrict__ be,
    float* __restrict__ out)
{
  const int tid = threadIdx.x, lane = tid & 63;
  const int row = blockIdx.x * 4 + (tid >> 6);
  const u16* ap = a + (size_t)row * D;
  const float* q0 = p0 + (size_t)row * D;
  const float* q1 = p1 + (size_t)row * D;
  float hv[16];
  float s = 0.f;
#pragma unroll
  for (int c4 = 0; c4 < 4; c4++) {
    int d = c4 * 256 + lane * 4;
    float a4[4], x4[4], y4[4], b4[4];
    ld4(ap, d, a4); ld4(q0, d, x4); ld4(q1, d, y4); ld4(bias, d, b4);
#pragma unroll
    for (int j = 0; j < 4; j++) {
      hv[c4 * 4 + j] = a4[j] + x4[j] + y4[j] + b4[j];
      s += hv[c4 * 4 + j];
    }
  }
#pragma unroll
  for (int d = 1; d < 64; d <<= 1) s += __shfl_xor(s, d);
  float mean = s * (1.0f / D);
  float v = 0.f;
#pragma unroll
  for (int c = 0; c < 16; c++) { float t = hv[c] - mean; v += t * t; }
#pragma unroll
  for (int d = 1; d < 64; d <<= 1) v += __shfl_xor(v, d);
  float inv = rsqrtf(v * (1.0f / D) + 1e-12f);
#pragma unroll
  for (int c4 = 0; c4 < 4; c4++) {
    int d = c4 * 256 + lane * 4;
    float g4[4], b4[4], o4[4];
    ld4(g, d, g4); ld4(be, d, b4);
#pragma unroll
    for (int j = 0; j < 4; j++) o4[j] = g4[j] * ((hv[c4 * 4 + j] - mean) * inv) + b4[j];
    st4(out + (size_t)row * D, d, o4);
  }
}

// ---------------------------------------------------------------------------
extern "C" void kernel_launch(void* const* d_in, const int* in_sizes, int n_in,
                              void* d_out, int out_size, void* d_ws, size_t ws_size,
                              hipStream_t stream)
{
  const float* x  = (const float*)d_in[0];
  const int* mask = (const int*)d_in[1];
  const float* wq = (const float*)d_in[2];  const float* bq  = (const float*)d_in[3];
  const float* wk = (const float*)d_in[4];  const float* bk  = (const float*)d_in[5];
  const float* wv = (const float*)d_in[6];  const float* bv  = (const float*)d_in[7];
  const float* wo = (const float*)d_in[8];  const float* bo  = (const float*)d_in[9];
  const float* g1 = (const float*)d_in[10]; const float* b1  = (const float*)d_in[11];
  const float* w1 = (const float*)d_in[12]; const float* bf1 = (const float*)d_in[13];
  const float* w2 = (const float*)d_in[14]; const float* bf2 = (const float*)d_in[15];
  const float* g2 = (const float*)d_in[16]; const float* b2  = (const float*)d_in[17];

  // ws layout (base 48 MB; split-K FFN2 uses [48,64M) when available):
  //  A [0,8M):   wqkvT(6M)+woT(2M); wqkvT dead after QKV -> l_parts(512KB)
  //              lives at [0,0.5M) during fattn; then w1T(8M) -> w2T(8M)
  //  B [8,16M):  xb -> vt -> ff1[0:8M)
  //  C [16,24M): q  -> proj -> ff1[8:16M)
  //  D [24,32M): k  -> ff1[16:24M)
  //  E [32,48M): v(8M, dead after transpose_v) -> o_parts(16M); combine
  //              writes attn in-place over half 0 ([32,40M)) -> ff1[24:32M)
  //  F [40,48M): bqkv(12KB, dead by fattn) -> o_parts half1 -> h1
  //  G [48,64M): FFN2 split-K partial1 (fp32, 16M) -- only if ws_size allows
  //  ff2 partial0 -> d_out; LN2 in place on d_out.
  char* ws = (char*)d_ws;
  const size_t MB = 1024 * 1024;
  u16* wqkvT = (u16*)(ws + 0 * MB);          // (3072, 1024) bf16 (+woT after)
  u16* w1T   = (u16*)(ws + 0 * MB);          // (4096, 1024) after proj
  u16* w2T   = (u16*)(ws + 0 * MB);          // (1024, 4096) after ffn1
  u16* woT   = (u16*)(ws + 6 * MB);          // (1024, 1024)
  u16* xb    = (u16*)(ws + 8 * MB);
  u16* vt    = (u16*)(ws + 8 * MB);
  u16* q     = (u16*)(ws + 16 * MB);
  u16* proj  = (u16*)(ws + 16 * MB);
  u16* kb    = (u16*)(ws + 24 * MB);
  u16* vb    = (u16*)(ws + 32 * MB);
  u16* oparts = (u16*)(ws + 32 * MB);        // 16 MB: 2 x (M,D) bf16 partials
  float* lparts = (float*)(ws + 0 * MB);     // 512 KB: 2 x (M,H) f32
  u16* attn  = (u16*)(ws + 32 * MB);         // combine output (aliases half0)
  u16* ff1   = (u16*)(ws + 8 * MB);          // 32 MB: [8,40)
  float* bqkv = (float*)(ws + 40 * MB);      // 12 KB
  u16* h1    = (u16*)(ws + 40 * MB);
  float* part1 = (float*)(ws + 48 * MB);     // 16 MB (gated on ws_size)
  float* out = (float*)d_out;

  const bool bigws = ws_size >= (size_t)64 * MB;

  dim3 blk(256);

  // prep: x -> bf16; 4 weight transposes in ONE dispatch; bias concat
  conv_x_kernel<<<dim3(M * D / 1024), blk, 0, stream>>>(x, xb);
  transpose_w4_kernel<<<dim3(16, 16, 4), blk, 0, stream>>>(wq, wk, wv, wo, wqkvT);
  hipMemcpyAsync(bqkv,        bq, D * sizeof(float), hipMemcpyDeviceToDevice, stream);
  hipMemcpyAsync(bqkv + 1024, bk, D * sizeof(float), hipMemcpyDeviceToDevice, stream);
  hipMemcpyAsync(bqkv + 2048, bv, D * sizeof(float), hipMemcpyDeviceToDevice, stream);

  // fused QKV GEMM: 256x192 tiles -> grid (16,16) = 256 blocks = 1/CU
  // (r12 full-fill fix; was 192 blocks = 75% fill).
  gemm256_qkv<<<dim3(3072 / 192, M / 256), dim3(512), 0, stream>>>(
      xb, wqkvT, bqkv, q, 0.125f);

  transpose_v_kernel<<<dim3(S / 64, Bb * H), blk, 0, stream>>>(vb, vt);
  // key-split flash attention: QBLK=256, 512 blocks, partials
  fattn_kernel<<<dim3(S / 256, Bb * H, 2), blk, 0, stream>>>(
      q, kb, vt, mask, oparts, lparts);
  combine_attn<<<dim3(M * D / 2048), blk, 0, stream>>>(oparts, lparts, attn);

  // proj: N=1024 -> 128x64 tiles (512 blocks, 2/CU)
  gemm_bt_n64<u16><<<dim3(D / 64, M / 128), blk, 0, stream>>>(
      attn, woT, bo, proj, D, D);
  ln_res_kernel<float, u16, u16><<<dim3(M / 4), blk, 0, stream>>>(x, proj, g1, b1, h1);

  transpose_w_kernel<<<dim3(F / 64, D / 64), blk, 0, stream>>>(w1, w1T, D, F);
  // FFN1: 256^2 merged-2-phase GEMM, 256 blocks
  gemm256<4096, 1024, 1, true><<<dim3(F / 256, M / 256), dim3(512), 0, stream>>>(
      h1, w1T, bf1, ff1, 1.0f);

  transpose_w_kernel<<<dim3(D / 64, F / 64), blk, 0, stream>>>(w2, w2T, F, D);
  if (bigws) {
    // FFN2: 256x128-tile 8-phase split-K (256 blocks = 1/CU), fp32 partials;
    // LN2 fuses the combine: out = LN(h1 + p0 + p1 + bf2)
    gemm_ffn2_splitk<<<dim3(D / 128, M / 256, 2), dim3(512), 0, stream>>>(
        ff1, w2T, out, part1);
    ln_res3_kernel<<<dim3(M / 4), blk, 0, stream>>>(h1, out, part1, bf2, g2, b2, out);
  } else {
    // fallback (small workspace): 2-phase 128x64 FFN2 + 2-input LN2
    gemm_bt_n64<float><<<dim3(D / 64, M / 128), blk, 0, stream>>>(
        ff1, w2T, bf2, out, D, F);
    ln_res_kernel<u16, float, float><<<dim3(M / 4), blk, 0, stream>>>(h1, out, g2, b2, out);
  }
}